// Round 1
// baseline (468.943 us; speedup 1.0000x reference)
//
#include <hip/hip_runtime.h>
#include <hip/hip_bf16.h>

#define SQ 4096
#define SKK 4096
#define DIN 768
#define AHS 384
#define NHEAD 12
#define HD 32

typedef __attribute__((ext_vector_type(8))) short bf16x8;
typedef __attribute__((ext_vector_type(4))) float f32x4;

__device__ __forceinline__ unsigned short bf16_rn(float x){
  unsigned int u = __float_as_uint(x);
  unsigned int r = u + 0x7fffu + ((u>>16)&1u);
  return (unsigned short)(r>>16);
}
__device__ __forceinline__ float bf16_f(unsigned short h){
  return __uint_as_float(((unsigned int)h)<<16);
}

// ---------------- prep: W -> W^T split into bf16 hi/lo ----------------
__global__ void prep_wt_kernel(const float* __restrict__ Wq, const float* __restrict__ Wk,
                               const float* __restrict__ Wv,
                               unsigned short* __restrict__ Wthi, unsigned short* __restrict__ Wtlo){
  int idx = blockIdx.x*256 + threadIdx.x;
  const int per = DIN*AHS;
  if (idx >= 3*per) return;
  int mat = idx/per, rem = idx - mat*per;
  int k = rem/AHS, n = rem - k*AHS;
  const float* W = (mat==0)?Wq:((mat==1)?Wk:Wv);
  float v = W[k*AHS+n];
  unsigned short hh = bf16_rn(v);
  unsigned short ll = bf16_rn(v - bf16_f(hh));
  Wthi[mat*per + n*DIN + k] = hh;
  Wtlo[mat*per + n*DIN + k] = ll;
}

// ---------------- QKV projection GEMM (split-bf16, 3 terms) ----------------
// z=0: Q = hidden @ Wq + bq, scaled by 1/sqrt(32), row-major hi/lo
// z=1: K = encoder @ Wk + bk, row-major hi/lo
// z=2: V = encoder @ Wv + bv, TRANSPOSED [AHS][SKK] hi/lo
__global__ __launch_bounds__(256) void proj_kernel(
    const float* __restrict__ Xh, const float* __restrict__ Xe,
    const unsigned short* __restrict__ Wthi, const unsigned short* __restrict__ Wtlo,
    const float* __restrict__ bq, const float* __restrict__ bk, const float* __restrict__ bv,
    unsigned short* __restrict__ Qhi, unsigned short* __restrict__ Qlo,
    unsigned short* __restrict__ Khi, unsigned short* __restrict__ Klo,
    unsigned short* __restrict__ Vthi, unsigned short* __restrict__ Vtlo)
{
  const int z = blockIdx.z;
  const float* X    = (z==0) ? Xh : Xe;
  const float* bias = (z==0) ? bq : ((z==1) ? bk : bv);
  const unsigned short* Wh = Wthi + (size_t)z*(DIN*AHS);
  const unsigned short* Wl = Wtlo + (size_t)z*(DIN*AHS);

  const int m0 = blockIdx.x*64;
  const int n0 = blockIdx.y*128;
  const int w  = threadIdx.x>>6, lane = threadIdx.x&63;
  const int lm = lane&15, g = lane>>4;
  const int wm = w>>1, wn = w&1;     // 2x2 waves, wave tile 32x64

  f32x4 acc[2][4];
  for (int mi=0;mi<2;++mi) for (int ni=0;ni<4;++ni) acc[mi][ni] = (f32x4){0.f,0.f,0.f,0.f};

  for (int kk=0; kk<DIN; kk+=32){
    bf16x8 ahf[2], alf[2];
    for (int mi=0; mi<2; ++mi){
      int row = m0 + wm*32 + mi*16 + lm;
      const float* xp = X + (size_t)row*DIN + kk + g*8;
      f32x4 x0 = *(const f32x4*)(xp);
      f32x4 x1 = *(const f32x4*)(xp+4);
      bf16x8 ah, al;
      #pragma unroll
      for (int i=0;i<4;i++){
        unsigned short h0 = bf16_rn(x0[i]);
        ah[i] = (short)h0; al[i] = (short)bf16_rn(x0[i] - bf16_f(h0));
        unsigned short h1 = bf16_rn(x1[i]);
        ah[4+i] = (short)h1; al[4+i] = (short)bf16_rn(x1[i] - bf16_f(h1));
      }
      ahf[mi]=ah; alf[mi]=al;
    }
    #pragma unroll
    for (int ni=0; ni<4; ++ni){
      int col = n0 + wn*64 + ni*16 + lm;
      bf16x8 bh = *(const bf16x8*)(Wh + (size_t)col*DIN + kk + g*8);
      bf16x8 bl = *(const bf16x8*)(Wl + (size_t)col*DIN + kk + g*8);
      #pragma unroll
      for (int mi=0; mi<2; ++mi){
        acc[mi][ni] = __builtin_amdgcn_mfma_f32_16x16x32_bf16(ahf[mi], bh, acc[mi][ni], 0,0,0);
        acc[mi][ni] = __builtin_amdgcn_mfma_f32_16x16x32_bf16(ahf[mi], bl, acc[mi][ni], 0,0,0);
        acc[mi][ni] = __builtin_amdgcn_mfma_f32_16x16x32_bf16(alf[mi], bh, acc[mi][ni], 0,0,0);
      }
    }
  }

  const float qscale = 0.17677669529663687f; // 1/sqrt(32)
  for (int ni=0; ni<4; ++ni){
    int col = n0 + wn*64 + ni*16 + lm;
    float bcol = bias[col];
    for (int mi=0; mi<2; ++mi){
      #pragma unroll
      for (int r=0; r<4; ++r){
        int row = m0 + wm*32 + mi*16 + g*4 + r;
        float v = acc[mi][ni][r] + bcol;
        if (z==0) v *= qscale;
        unsigned short hh = bf16_rn(v);
        unsigned short ll = bf16_rn(v - bf16_f(hh));
        if (z==0)      { Qhi[(size_t)row*AHS+col]=hh; Qlo[(size_t)row*AHS+col]=ll; }
        else if (z==1) { Khi[(size_t)row*AHS+col]=hh; Klo[(size_t)row*AHS+col]=ll; }
        else           { Vthi[(size_t)col*SKK+row]=hh; Vtlo[(size_t)col*SKK+row]=ll; }
      }
    }
  }
}

// ---------------- fused flash attention ----------------
// grid (SQ/64, NHEAD), 256 threads = 4 waves; wave w owns q-rows qt*64+w*16..+15
__global__ __launch_bounds__(256) void attn_kernel(
    const unsigned short* __restrict__ Qhi, const unsigned short* __restrict__ Qlo,
    const unsigned short* __restrict__ Khi, const unsigned short* __restrict__ Klo,
    const unsigned short* __restrict__ Vthi, const unsigned short* __restrict__ Vtlo,
    const float* __restrict__ mask, float* __restrict__ out)
{
  const int qt = blockIdx.x, h = blockIdx.y;
  const int w = threadIdx.x>>6, lane = threadIdx.x&63;
  const int lm = lane&15, g = lane>>4;
  const int qrow = qt*64 + w*16 + lm;

  __shared__ unsigned short Ph[64][72];  // +8 pad -> 2-way bank conflict only (free)
  __shared__ unsigned short Pl[64][72];

  bf16x8 qh = *(const bf16x8*)(Qhi + (size_t)qrow*AHS + h*HD + g*8);
  bf16x8 ql = *(const bf16x8*)(Qlo + (size_t)qrow*AHS + h*HD + g*8);

  f32x4 o0 = {0.f,0.f,0.f,0.f}, o1 = {0.f,0.f,0.f,0.f};
  float mr[4], lr[4];
  #pragma unroll
  for (int r=0;r<4;++r){ mr[r] = -3.0e38f; lr[r] = 0.f; }

  for (int kt=0; kt<SKK; kt+=64){
    // ---- scores: S[16q x 64k], 3 split terms ----
    f32x4 s[4];
    #pragma unroll
    for (int ks=0; ks<4; ++ks){
      int key = kt + ks*16 + lm;
      bf16x8 kh = *(const bf16x8*)(Khi + (size_t)key*AHS + h*HD + g*8);
      bf16x8 kl = *(const bf16x8*)(Klo + (size_t)key*AHS + h*HD + g*8);
      f32x4 a = {0.f,0.f,0.f,0.f};
      a = __builtin_amdgcn_mfma_f32_16x16x32_bf16(qh, kh, a, 0,0,0);
      a = __builtin_amdgcn_mfma_f32_16x16x32_bf16(qh, kl, a, 0,0,0);
      a = __builtin_amdgcn_mfma_f32_16x16x32_bf16(ql, kh, a, 0,0,0);
      float mk = mask[key];
      #pragma unroll
      for (int r=0;r<4;++r) a[r] += mk;
      s[ks] = a;
    }

    // ---- row max (over 64 keys): in-lane over ks, then across 16 lanes ----
    float mn[4], sc[4];
    #pragma unroll
    for (int r=0;r<4;++r){
      float t = fmaxf(fmaxf(s[0][r],s[1][r]), fmaxf(s[2][r],s[3][r]));
      for (int off=1; off<16; off<<=1) t = fmaxf(t, __shfl_xor(t, off));
      mn[r] = fmaxf(mr[r], t);
      sc[r] = __expf(mr[r] - mn[r]);
    }

    // ---- P = exp(s - m), split to bf16 hi/lo, stash in wave-private LDS ----
    float ts[4] = {0.f,0.f,0.f,0.f};
    const int prow = w*16 + g*4;
    #pragma unroll
    for (int ks=0; ks<4; ++ks){
      #pragma unroll
      for (int r=0;r<4;++r){
        float p = __expf(s[ks][r] - mn[r]);
        ts[r] += p;
        unsigned short ph = bf16_rn(p);
        unsigned short pl = bf16_rn(p - bf16_f(ph));
        Ph[prow + r][ks*16 + lm] = ph;
        Pl[prow + r][ks*16 + lm] = pl;
      }
    }
    #pragma unroll
    for (int r=0;r<4;++r){
      float t = ts[r];
      for (int off=1; off<16; off<<=1) t += __shfl_xor(t, off);
      lr[r] = lr[r]*sc[r] + t;
      mr[r] = mn[r];
      o0[r] *= sc[r]; o1[r] *= sc[r];
    }

    // ---- PV: ctx += P[16q x 64k] @ V[64k x 32d], 3 split terms ----
    #pragma unroll
    for (int ks2=0; ks2<2; ++ks2){
      bf16x8 pah = *(const bf16x8*)&Ph[w*16 + lm][ks2*32 + g*8];
      bf16x8 pal = *(const bf16x8*)&Pl[w*16 + lm][ks2*32 + g*8];
      {
        const unsigned short* vph = Vthi + (size_t)(h*HD + lm)*SKK + kt + ks2*32 + g*8;
        const unsigned short* vpl = Vtlo + (size_t)(h*HD + lm)*SKK + kt + ks2*32 + g*8;
        bf16x8 vh = *(const bf16x8*)vph;
        bf16x8 vl = *(const bf16x8*)vpl;
        o0 = __builtin_amdgcn_mfma_f32_16x16x32_bf16(pah, vh, o0, 0,0,0);
        o0 = __builtin_amdgcn_mfma_f32_16x16x32_bf16(pah, vl, o0, 0,0,0);
        o0 = __builtin_amdgcn_mfma_f32_16x16x32_bf16(pal, vh, o0, 0,0,0);
      }
      {
        const unsigned short* vph = Vthi + (size_t)(h*HD + 16 + lm)*SKK + kt + ks2*32 + g*8;
        const unsigned short* vpl = Vtlo + (size_t)(h*HD + 16 + lm)*SKK + kt + ks2*32 + g*8;
        bf16x8 vh = *(const bf16x8*)vph;
        bf16x8 vl = *(const bf16x8*)vpl;
        o1 = __builtin_amdgcn_mfma_f32_16x16x32_bf16(pah, vh, o1, 0,0,0);
        o1 = __builtin_amdgcn_mfma_f32_16x16x32_bf16(pah, vl, o1, 0,0,0);
        o1 = __builtin_amdgcn_mfma_f32_16x16x32_bf16(pal, vh, o1, 0,0,0);
      }
    }
  }

  // ---- epilogue: divide by row sums, write fp32 out ----
  #pragma unroll
  for (int r=0;r<4;++r){
    float inv = 1.0f / lr[r];
    int row = qt*64 + w*16 + g*4 + r;
    out[(size_t)row*AHS + h*HD + lm]      = o0[r]*inv;
    out[(size_t)row*AHS + h*HD + 16 + lm] = o1[r]*inv;
  }
}

extern "C" void kernel_launch(void* const* d_in, const int* in_sizes, int n_in,
                              void* d_out, int out_size, void* d_ws, size_t ws_size,
                              hipStream_t stream) {
  const float* Xh   = (const float*)d_in[0];  // hidden_states   [1,4096,768]
  const float* Xe   = (const float*)d_in[1];  // encoder_hidden  [1,4096,768]
  const float* mask = (const float*)d_in[2];  // [1,1,1,4096]
  const float* Wq   = (const float*)d_in[3];
  const float* bq   = (const float*)d_in[4];
  const float* Wk   = (const float*)d_in[5];
  const float* bk   = (const float*)d_in[6];
  const float* Wv   = (const float*)d_in[7];
  const float* bv   = (const float*)d_in[8];
  float* out = (float*)d_out;

  char* ws = (char*)d_ws;
  size_t off = 0;
  auto alloc = [&](size_t bytes)->void*{
    void* p = ws + off;
    off += (bytes + 255) & ~(size_t)255;
    return p;
  };
  unsigned short* Wthi = (unsigned short*)alloc((size_t)3*DIN*AHS*2);
  unsigned short* Wtlo = (unsigned short*)alloc((size_t)3*DIN*AHS*2);
  unsigned short* Qhi  = (unsigned short*)alloc((size_t)SQ*AHS*2);
  unsigned short* Qlo  = (unsigned short*)alloc((size_t)SQ*AHS*2);
  unsigned short* Khi  = (unsigned short*)alloc((size_t)SKK*AHS*2);
  unsigned short* Klo  = (unsigned short*)alloc((size_t)SKK*AHS*2);
  unsigned short* Vthi = (unsigned short*)alloc((size_t)AHS*SKK*2);
  unsigned short* Vtlo = (unsigned short*)alloc((size_t)AHS*SKK*2);
  // total ~22.5 MB of d_ws

  {
    int tot = 3*DIN*AHS;
    prep_wt_kernel<<<(tot+255)/256, 256, 0, stream>>>(Wq, Wk, Wv, Wthi, Wtlo);
  }
  {
    dim3 grid(SQ/64, AHS/128, 3);
    proj_kernel<<<grid, 256, 0, stream>>>(Xh, Xe, Wthi, Wtlo, bq, bk, bv,
                                          Qhi, Qlo, Khi, Klo, Vthi, Vtlo);
  }
  {
    dim3 grid(SQ/64, NHEAD);
    attn_kernel<<<grid, 256, 0, stream>>>(Qhi, Qlo, Khi, Klo, Vthi, Vtlo, mask, out);
  }
}

// Round 2
// 393.483 us; speedup vs baseline: 1.1918x; 1.1918x over previous
//
#include <hip/hip_runtime.h>
#include <hip/hip_bf16.h>

#define SQ 4096
#define SKK 4096
#define DIN 768
#define AHS 384
#define NHEAD 12
#define HD 32

typedef __attribute__((ext_vector_type(8))) short bf16x8;
typedef __attribute__((ext_vector_type(4))) float f32x4;

__device__ __forceinline__ unsigned short bf16_rn(float x){
  unsigned int u = __float_as_uint(x);
  unsigned int r = u + 0x7fffu + ((u>>16)&1u);
  return (unsigned short)(r>>16);
}
__device__ __forceinline__ float bf16_f(unsigned short h){
  return __uint_as_float(((unsigned int)h)<<16);
}

// ---------------- prep: W -> W^T split into bf16 hi/lo ----------------
__global__ void prep_wt_kernel(const float* __restrict__ Wq, const float* __restrict__ Wk,
                               const float* __restrict__ Wv,
                               unsigned short* __restrict__ Wthi, unsigned short* __restrict__ Wtlo){
  int idx = blockIdx.x*256 + threadIdx.x;
  const int per = DIN*AHS;
  if (idx >= 3*per) return;
  int mat = idx/per, rem = idx - mat*per;
  int k = rem/AHS, n = rem - k*AHS;
  const float* W = (mat==0)?Wq:((mat==1)?Wk:Wv);
  float v = W[k*AHS+n];
  unsigned short hh = bf16_rn(v);
  unsigned short ll = bf16_rn(v - bf16_f(hh));
  Wthi[mat*per + n*DIN + k] = hh;
  Wtlo[mat*per + n*DIN + k] = ll;
}

// ---------------- QKV projection GEMM ----------------
// z=0: Q (scaled by 1/sqrt(32)) hi/lo row-major; z=1: K hi/lo row-major;
// z=2: V bf16 (hi only), TRANSPOSED [AHS][SKK]
__global__ __launch_bounds__(256) void proj_kernel(
    const float* __restrict__ Xh, const float* __restrict__ Xe,
    const unsigned short* __restrict__ Wthi, const unsigned short* __restrict__ Wtlo,
    const float* __restrict__ bq, const float* __restrict__ bk, const float* __restrict__ bv,
    unsigned short* __restrict__ Qhi, unsigned short* __restrict__ Qlo,
    unsigned short* __restrict__ Khi, unsigned short* __restrict__ Klo,
    unsigned short* __restrict__ Vt)
{
  const int z = blockIdx.z;
  const float* X    = (z==0) ? Xh : Xe;
  const float* bias = (z==0) ? bq : ((z==1) ? bk : bv);
  const unsigned short* Wh = Wthi + (size_t)z*(DIN*AHS);
  const unsigned short* Wl = Wtlo + (size_t)z*(DIN*AHS);

  const int m0 = blockIdx.x*64;
  const int n0 = blockIdx.y*128;
  const int w  = threadIdx.x>>6, lane = threadIdx.x&63;
  const int lm = lane&15, g = lane>>4;
  const int wm = w>>1, wn = w&1;     // 2x2 waves, wave tile 32x64

  f32x4 acc[2][4];
  for (int mi=0;mi<2;++mi) for (int ni=0;ni<4;++ni) acc[mi][ni] = (f32x4){0.f,0.f,0.f,0.f};

  for (int kk=0; kk<DIN; kk+=32){
    bf16x8 ahf[2], alf[2];
    for (int mi=0; mi<2; ++mi){
      int row = m0 + wm*32 + mi*16 + lm;
      const float* xp = X + (size_t)row*DIN + kk + g*8;
      f32x4 x0 = *(const f32x4*)(xp);
      f32x4 x1 = *(const f32x4*)(xp+4);
      bf16x8 ah, al;
      #pragma unroll
      for (int i=0;i<4;i++){
        unsigned short h0 = bf16_rn(x0[i]);
        ah[i] = (short)h0; al[i] = (short)bf16_rn(x0[i] - bf16_f(h0));
        unsigned short h1 = bf16_rn(x1[i]);
        ah[4+i] = (short)h1; al[4+i] = (short)bf16_rn(x1[i] - bf16_f(h1));
      }
      ahf[mi]=ah; alf[mi]=al;
    }
    #pragma unroll
    for (int ni=0; ni<4; ++ni){
      int col = n0 + wn*64 + ni*16 + lm;
      bf16x8 bh = *(const bf16x8*)(Wh + (size_t)col*DIN + kk + g*8);
      bf16x8 bl = *(const bf16x8*)(Wl + (size_t)col*DIN + kk + g*8);
      #pragma unroll
      for (int mi=0; mi<2; ++mi){
        acc[mi][ni] = __builtin_amdgcn_mfma_f32_16x16x32_bf16(ahf[mi], bh, acc[mi][ni], 0,0,0);
        if (z != 2){  // V gets bf16-rounded anyway; hi-term suffices
          acc[mi][ni] = __builtin_amdgcn_mfma_f32_16x16x32_bf16(ahf[mi], bl, acc[mi][ni], 0,0,0);
          acc[mi][ni] = __builtin_amdgcn_mfma_f32_16x16x32_bf16(alf[mi], bh, acc[mi][ni], 0,0,0);
        }
      }
    }
  }

  const float qscale = 0.17677669529663687f; // 1/sqrt(32)
  for (int ni=0; ni<4; ++ni){
    int col = n0 + wn*64 + ni*16 + lm;
    float bcol = bias[col];
    for (int mi=0; mi<2; ++mi){
      #pragma unroll
      for (int r=0; r<4; ++r){
        int row = m0 + wm*32 + mi*16 + g*4 + r;
        float v = acc[mi][ni][r] + bcol;
        if (z==0) v *= qscale;
        unsigned short hh = bf16_rn(v);
        if (z==0)      { unsigned short ll = bf16_rn(v - bf16_f(hh));
                         Qhi[(size_t)row*AHS+col]=hh; Qlo[(size_t)row*AHS+col]=ll; }
        else if (z==1) { unsigned short ll = bf16_rn(v - bf16_f(hh));
                         Khi[(size_t)row*AHS+col]=hh; Klo[(size_t)row*AHS+col]=ll; }
        else           { Vt[(size_t)col*SKK+row]=hh; }
      }
    }
  }
}

// ---------------- fused flash attention, split-K ----------------
// grid (SQ/64, NHEAD, S); 4 waves/block, wave w owns q-rows qt*64+w*16..+15
// Each split handles nkt tiles of 64 keys; writes unnormalized o + (m,l),
// or (direct mode) normalized output.
__global__ __launch_bounds__(256,4) void attn_kernel(
    const unsigned short* __restrict__ Qhi, const unsigned short* __restrict__ Qlo,
    const unsigned short* __restrict__ Khi, const unsigned short* __restrict__ Klo,
    const unsigned short* __restrict__ Vt,
    const float* __restrict__ mask,
    float* __restrict__ opart, float* __restrict__ mpart, float* __restrict__ lpart,
    int nkt, int direct)
{
  const int qt = blockIdx.x, h = blockIdx.y, sp = blockIdx.z;
  const int w = threadIdx.x>>6, lane = threadIdx.x&63;
  const int lm = lane&15, g = lane>>4;
  const int qrow = qt*64 + w*16 + lm;
  const int kbeg = sp*nkt*64;

  __shared__ unsigned short Ph[64][72];

  bf16x8 qh = *(const bf16x8*)(Qhi + (size_t)qrow*AHS + h*HD + g*8);
  bf16x8 ql = *(const bf16x8*)(Qlo + (size_t)qrow*AHS + h*HD + g*8);

  f32x4 o0 = {0.f,0.f,0.f,0.f}, o1 = {0.f,0.f,0.f,0.f};
  float m[4], lsum[4];
  #pragma unroll
  for (int r=0;r<4;++r){ m[r] = -3.0e38f; lsum[r] = 0.f; }

  // prologue: K tile 0 of this split
  bf16x8 kh[4], kl[4];
  #pragma unroll
  for (int ks=0; ks<4; ++ks){
    int key = kbeg + ks*16 + lm;
    kh[ks] = *(const bf16x8*)(Khi + (size_t)key*AHS + h*HD + g*8);
    kl[ks] = *(const bf16x8*)(Klo + (size_t)key*AHS + h*HD + g*8);
  }

  for (int t=0; t<nkt; ++t){
    const int kt = kbeg + t*64;

    // ---- scores S[16q x 64k], 3 split terms, consume current K regs ----
    f32x4 s[4];
    #pragma unroll
    for (int ks=0; ks<4; ++ks){
      f32x4 a = {0.f,0.f,0.f,0.f};
      a = __builtin_amdgcn_mfma_f32_16x16x32_bf16(qh, kh[ks], a, 0,0,0);
      a = __builtin_amdgcn_mfma_f32_16x16x32_bf16(qh, kl[ks], a, 0,0,0);
      a = __builtin_amdgcn_mfma_f32_16x16x32_bf16(ql, kh[ks], a, 0,0,0);
      float mk = mask[kt + ks*16 + lm];
      #pragma unroll
      for (int r=0;r<4;++r) a[r] += mk;
      s[ks] = a;
    }

    // ---- prefetch next K tile (latency hidden under softmax + PV) ----
    if (t+1 < nkt){
      #pragma unroll
      for (int ks=0; ks<4; ++ks){
        int key = kt + 64 + ks*16 + lm;
        kh[ks] = *(const bf16x8*)(Khi + (size_t)key*AHS + h*HD + g*8);
        kl[ks] = *(const bf16x8*)(Klo + (size_t)key*AHS + h*HD + g*8);
      }
    }

    // ---- V loads for this tile (latency hidden under softmax) ----
    bf16x8 v0[2], v1[2];
    #pragma unroll
    for (int ks2=0; ks2<2; ++ks2){
      v0[ks2] = *(const bf16x8*)(Vt + (size_t)(h*HD + lm)*SKK + kt + ks2*32 + g*8);
      v1[ks2] = *(const bf16x8*)(Vt + (size_t)(h*HD + 16 + lm)*SKK + kt + ks2*32 + g*8);
    }

    // ---- defer-max: per-lane tile max, ballot fast path ----
    float tl[4];
    #pragma unroll
    for (int r=0;r<4;++r)
      tl[r] = fmaxf(fmaxf(s[0][r],s[1][r]), fmaxf(s[2][r],s[3][r]));
    bool ok = (tl[0] <= m[0]+8.f) && (tl[1] <= m[1]+8.f) &&
              (tl[2] <= m[2]+8.f) && (tl[3] <= m[3]+8.f);
    if (__ballot(ok) != ~0ULL){
      // slow path: true row max, rescale running state
      #pragma unroll
      for (int r=0;r<4;++r){
        float t2 = tl[r];
        #pragma unroll
        for (int off=1; off<16; off<<=1) t2 = fmaxf(t2, __shfl_xor(t2, off));
        float mn = fmaxf(m[r], t2);
        float sc = __expf(m[r] - mn);
        o0[r] *= sc; o1[r] *= sc; lsum[r] *= sc;
        m[r] = mn;
      }
    }

    // ---- P = exp(s-m) (bounded by e^8), bf16-hi only, lane-partial sums ----
    const int prow = w*16 + g*4;
    #pragma unroll
    for (int ks=0; ks<4; ++ks){
      #pragma unroll
      for (int r=0;r<4;++r){
        float p = __expf(s[ks][r] - m[r]);
        lsum[r] += p;
        Ph[prow + r][ks*16 + lm] = bf16_rn(p);
      }
    }

    // ---- PV: ctx += P @ V (P hi, V single bf16) ----
    #pragma unroll
    for (int ks2=0; ks2<2; ++ks2){
      bf16x8 pa = *(const bf16x8*)&Ph[w*16 + lm][ks2*32 + g*8];
      o0 = __builtin_amdgcn_mfma_f32_16x16x32_bf16(pa, v0[ks2], o0, 0,0,0);
      o1 = __builtin_amdgcn_mfma_f32_16x16x32_bf16(pa, v1[ks2], o1, 0,0,0);
    }
  }

  // ---- final row-sum reduce (once, not per tile) ----
  float L[4];
  #pragma unroll
  for (int r=0;r<4;++r){
    float t2 = lsum[r];
    #pragma unroll
    for (int off=1; off<16; off<<=1) t2 += __shfl_xor(t2, off);
    L[r] = t2;
  }

  if (direct){
    #pragma unroll
    for (int r=0;r<4;++r){
      float inv = 1.0f / L[r];
      int row = qt*64 + w*16 + g*4 + r;
      opart[(size_t)row*AHS + h*HD + lm]      = o0[r]*inv;
      opart[(size_t)row*AHS + h*HD + 16 + lm] = o1[r]*inv;
    }
  } else {
    #pragma unroll
    for (int r=0;r<4;++r){
      int row = qt*64 + w*16 + g*4 + r;
      opart[((size_t)sp*SQ + row)*AHS + h*HD + lm]      = o0[r];
      opart[((size_t)sp*SQ + row)*AHS + h*HD + 16 + lm] = o1[r];
    }
    if (lm == 0){
      #pragma unroll
      for (int r=0;r<4;++r){
        int row = qt*64 + w*16 + g*4 + r;
        mpart[((size_t)sp*NHEAD + h)*SQ + row] = m[r];
        lpart[((size_t)sp*NHEAD + h)*SQ + row] = L[r];
      }
    }
  }
}

// ---------------- merge partial splits ----------------
__global__ void merge_kernel(const float* __restrict__ opart,
                             const float* __restrict__ mpart,
                             const float* __restrict__ lpart,
                             float* __restrict__ out, int S){
  int idx = blockIdx.x*256 + threadIdx.x;
  if (idx >= SQ*AHS) return;
  int row = idx/AHS, c = idx - row*AHS;
  int h = c >> 5;
  float M = -3.0e38f;
  for (int s=0; s<S; ++s) M = fmaxf(M, mpart[((size_t)s*NHEAD + h)*SQ + row]);
  float num = 0.f, den = 0.f;
  for (int s=0; s<S; ++s){
    float wgt = __expf(mpart[((size_t)s*NHEAD + h)*SQ + row] - M);
    num += wgt * opart[((size_t)s*SQ + row)*AHS + c];
    den += wgt * lpart[((size_t)s*NHEAD + h)*SQ + row];
  }
  out[idx] = num/den;
}

extern "C" void kernel_launch(void* const* d_in, const int* in_sizes, int n_in,
                              void* d_out, int out_size, void* d_ws, size_t ws_size,
                              hipStream_t stream) {
  const float* Xh   = (const float*)d_in[0];
  const float* Xe   = (const float*)d_in[1];
  const float* mask = (const float*)d_in[2];
  const float* Wq   = (const float*)d_in[3];
  const float* bq   = (const float*)d_in[4];
  const float* Wk   = (const float*)d_in[5];
  const float* bk   = (const float*)d_in[6];
  const float* Wv   = (const float*)d_in[7];
  const float* bv   = (const float*)d_in[8];
  float* out = (float*)d_out;

  char* ws = (char*)d_ws;
  size_t off = 0;
  auto alloc = [&](size_t bytes)->void*{
    void* p = ws + off;
    off += (bytes + 255) & ~(size_t)255;
    return p;
  };
  unsigned short* Wthi = (unsigned short*)alloc((size_t)3*DIN*AHS*2);
  unsigned short* Wtlo = (unsigned short*)alloc((size_t)3*DIN*AHS*2);
  unsigned short* Qhi  = (unsigned short*)alloc((size_t)SQ*AHS*2);
  unsigned short* Qlo  = (unsigned short*)alloc((size_t)SQ*AHS*2);
  unsigned short* Khi  = (unsigned short*)alloc((size_t)SKK*AHS*2);
  unsigned short* Klo  = (unsigned short*)alloc((size_t)SKK*AHS*2);
  unsigned short* Vt   = (unsigned short*)alloc((size_t)AHS*SKK*2);
  size_t base_end = off;

  const size_t o_bytes  = (size_t)SQ*AHS*4;
  const size_t ml_bytes = (size_t)NHEAD*SQ*4;
  const size_t per_split = ((o_bytes+255)&~(size_t)255) + 2*((ml_bytes+255)&~(size_t)255);

  int S, direct;
  if      (ws_size >= base_end + 4*per_split + 1024) { S = 4; direct = 0; }
  else if (ws_size >= base_end + 2*per_split + 1024) { S = 2; direct = 0; }
  else if (ws_size >= base_end + 1*per_split + 1024) { S = 1; direct = 0; }
  else                                               { S = 1; direct = 1; }

  float *opart, *mpart, *lpart;
  if (!direct){
    opart = (float*)alloc((size_t)S*((o_bytes+255)&~(size_t)255));
    mpart = (float*)alloc((size_t)S*((ml_bytes+255)&~(size_t)255));
    lpart = (float*)alloc((size_t)S*((ml_bytes+255)&~(size_t)255));
  } else {
    opart = out; mpart = (float*)ws; lpart = (float*)ws;  // unused in direct mode
  }

  {
    int tot = 3*DIN*AHS;
    prep_wt_kernel<<<(tot+255)/256, 256, 0, stream>>>(Wq, Wk, Wv, Wthi, Wtlo);
  }
  {
    dim3 grid(SQ/64, AHS/128, 3);
    proj_kernel<<<grid, 256, 0, stream>>>(Xh, Xe, Wthi, Wtlo, bq, bk, bv,
                                          Qhi, Qlo, Khi, Klo, Vt);
  }
  {
    dim3 grid(SQ/64, NHEAD, S);
    int nkt = (SKK/64)/S;
    attn_kernel<<<grid, 256, 0, stream>>>(Qhi, Qlo, Khi, Klo, Vt, mask,
                                          opart, mpart, lpart, nkt, direct);
  }
  if (!direct){
    int n = SQ*AHS;
    merge_kernel<<<(n+255)/256, 256, 0, stream>>>(opart, mpart, lpart, out, S);
  }
}

// Round 3
// 234.713 us; speedup vs baseline: 1.9979x; 1.6764x over previous
//
#include <hip/hip_runtime.h>
#include <hip/hip_bf16.h>

#define SQ 4096
#define SKK 4096
#define DIN 768
#define AHS 384
#define NHEAD 12
#define HD 32

typedef __attribute__((ext_vector_type(8))) short bf16x8;
typedef __attribute__((ext_vector_type(4))) float f32x4;
typedef __attribute__((ext_vector_type(4))) unsigned int u32x4;

__device__ __forceinline__ unsigned short bf16_rn(float x){
  unsigned int u = __float_as_uint(x);
  unsigned int r = u + 0x7fffu + ((u>>16)&1u);
  return (unsigned short)(r>>16);
}
__device__ __forceinline__ float bf16_f(unsigned short h){
  return __uint_as_float(((unsigned int)h)<<16);
}

// ---------------- prep: W -> W^T split into bf16 hi/lo ----------------
__global__ void prep_wt_kernel(const float* __restrict__ Wq, const float* __restrict__ Wk,
                               const float* __restrict__ Wv,
                               unsigned short* __restrict__ Wthi, unsigned short* __restrict__ Wtlo){
  int idx = blockIdx.x*256 + threadIdx.x;
  const int per = DIN*AHS;
  if (idx >= 3*per) return;
  int mat = idx/per, rem = idx - mat*per;
  int k = rem/AHS, n = rem - k*AHS;
  const float* W = (mat==0)?Wq:((mat==1)?Wk:Wv);
  float v = W[k*AHS+n];
  unsigned short hh = bf16_rn(v);
  unsigned short ll = bf16_rn(v - bf16_f(hh));
  Wthi[mat*per + n*DIN + k] = hh;
  Wtlo[mat*per + n*DIN + k] = ll;
}

// ---------------- QKV projection GEMM (64x64 tiles for TLP) ----------------
// z=0: Q (scaled 1/sqrt(32)) hi/lo HEAD-MAJOR [H][SQ][HD]
// z=1: K hi/lo HEAD-MAJOR [H][SKK][HD]
// z=2: V bf16 hi-only, TRANSPOSED [AHS][SKK]
__global__ __launch_bounds__(256) void proj_kernel(
    const float* __restrict__ Xh, const float* __restrict__ Xe,
    const unsigned short* __restrict__ Wthi, const unsigned short* __restrict__ Wtlo,
    const float* __restrict__ bq, const float* __restrict__ bk, const float* __restrict__ bv,
    unsigned short* __restrict__ Qhi, unsigned short* __restrict__ Qlo,
    unsigned short* __restrict__ Khi, unsigned short* __restrict__ Klo,
    unsigned short* __restrict__ Vt)
{
  const int z = blockIdx.z;
  const float* X    = (z==0) ? Xh : Xe;
  const float* bias = (z==0) ? bq : ((z==1) ? bk : bv);
  const unsigned short* Wh = Wthi + (size_t)z*(DIN*AHS);
  const unsigned short* Wl = Wtlo + (size_t)z*(DIN*AHS);

  const int m0 = blockIdx.x*64;
  const int n0 = blockIdx.y*64;
  const int w  = threadIdx.x>>6, lane = threadIdx.x&63;
  const int lm = lane&15, g = lane>>4;
  const int wm = w>>1, wn = w&1;     // 2x2 waves, wave tile 32x32

  f32x4 acc[2][2];
  for (int mi=0;mi<2;++mi) for (int ni=0;ni<2;++ni) acc[mi][ni] = (f32x4){0.f,0.f,0.f,0.f};

  for (int kk=0; kk<DIN; kk+=32){
    bf16x8 ahf[2], alf[2];
    for (int mi=0; mi<2; ++mi){
      int row = m0 + wm*32 + mi*16 + lm;
      const float* xp = X + (size_t)row*DIN + kk + g*8;
      f32x4 x0 = *(const f32x4*)(xp);
      f32x4 x1 = *(const f32x4*)(xp+4);
      bf16x8 ah, al;
      #pragma unroll
      for (int i=0;i<4;i++){
        unsigned short h0 = bf16_rn(x0[i]);
        ah[i] = (short)h0; al[i] = (short)bf16_rn(x0[i] - bf16_f(h0));
        unsigned short h1 = bf16_rn(x1[i]);
        ah[4+i] = (short)h1; al[4+i] = (short)bf16_rn(x1[i] - bf16_f(h1));
      }
      ahf[mi]=ah; alf[mi]=al;
    }
    #pragma unroll
    for (int ni=0; ni<2; ++ni){
      int col = n0 + wn*32 + ni*16 + lm;
      bf16x8 bh = *(const bf16x8*)(Wh + (size_t)col*DIN + kk + g*8);
      bf16x8 bl = *(const bf16x8*)(Wl + (size_t)col*DIN + kk + g*8);
      #pragma unroll
      for (int mi=0; mi<2; ++mi){
        acc[mi][ni] = __builtin_amdgcn_mfma_f32_16x16x32_bf16(ahf[mi], bh, acc[mi][ni], 0,0,0);
        if (z != 2){
          acc[mi][ni] = __builtin_amdgcn_mfma_f32_16x16x32_bf16(ahf[mi], bl, acc[mi][ni], 0,0,0);
          acc[mi][ni] = __builtin_amdgcn_mfma_f32_16x16x32_bf16(alf[mi], bh, acc[mi][ni], 0,0,0);
        }
      }
    }
  }

  const float qscale = 0.17677669529663687f; // 1/sqrt(32)
  for (int ni=0; ni<2; ++ni){
    int col = n0 + wn*32 + ni*16 + lm;
    float bcol = bias[col];
    int hq = col>>5, d = col&31;
    for (int mi=0; mi<2; ++mi){
      #pragma unroll
      for (int r=0; r<4; ++r){
        int row = m0 + wm*32 + mi*16 + g*4 + r;
        float v = acc[mi][ni][r] + bcol;
        if (z==0) v *= qscale;
        unsigned short hh = bf16_rn(v);
        if (z==0)      { unsigned short ll = bf16_rn(v - bf16_f(hh));
                         size_t p = ((size_t)hq*SQ + row)*HD + d;
                         Qhi[p]=hh; Qlo[p]=ll; }
        else if (z==1) { unsigned short ll = bf16_rn(v - bf16_f(hh));
                         size_t p = ((size_t)hq*SKK + row)*HD + d;
                         Khi[p]=hh; Klo[p]=ll; }
        else           { Vt[(size_t)col*SKK+row]=hh; }
      }
    }
  }
}

// ---------------- fused flash attention, split-K, LDS-staged K/V ----------------
// grid (SQ/64, NHEAD, S); 4 waves; wave w owns q-rows qt*64+w*16..+15
__global__ __launch_bounds__(256) void attn_kernel(
    const unsigned short* __restrict__ Qhi, const unsigned short* __restrict__ Qlo,
    const unsigned short* __restrict__ Khi, const unsigned short* __restrict__ Klo,
    const unsigned short* __restrict__ Vt,
    const float* __restrict__ mask,
    float* __restrict__ opart, float* __restrict__ mpart, float* __restrict__ lpart,
    int nkt, int direct)
{
  const int qt = blockIdx.x, h = blockIdx.y, sp = blockIdx.z;
  const int tid = threadIdx.x;
  const int w = tid>>6, lane = tid&63;
  const int lm = lane&15, g = lane>>4;
  const int qrow = qt*64 + w*16 + lm;
  const int kbeg = sp*nkt*64;

  // double-buffered K/V tiles (XOR-swizzled), plus P transpose buffer
  __shared__ unsigned short KhL[2][2048];   // 64 keys x 32 shorts (hi)
  __shared__ unsigned short KlL[2][2048];   // (lo)
  __shared__ unsigned short VL [2][2048];   // 32 d x 64 keys
  __shared__ unsigned short Ph[64][72];

  const unsigned short* Khg = Khi + (size_t)h*SKK*HD;
  const unsigned short* Klg = Klo + (size_t)h*SKK*HD;

  // staging addressing: thread tid moves 16B of each of Khi/Klo/V per tile
  const int krow_s = tid>>2, kcol_s = (tid&3)*8;
  const int vrow_s = tid>>3, vcol_s = (tid&7)*8;
  const int kd = (tid*8) ^ (((tid>>2)&3)<<3);   // swizzled LDS short-index
  const int vd = (tid*8) ^ (((tid>>3)&7)<<3);

  u32x4 sa, sb, sc;
  float mk_nxt[4], mk_cur[4];
  auto stage_load = [&](int kb){
    sa = *(const u32x4*)(Khg + (size_t)(kb + krow_s)*HD + kcol_s);
    sb = *(const u32x4*)(Klg + (size_t)(kb + krow_s)*HD + kcol_s);
    sc = *(const u32x4*)(Vt + (size_t)(h*HD + vrow_s)*SKK + kb + vcol_s);
    #pragma unroll
    for (int ks=0; ks<4; ++ks) mk_nxt[ks] = mask[kb + ks*16 + lm];
  };
  auto stage_write = [&](int b){
    *(u32x4*)(&KhL[b][kd]) = sa;
    *(u32x4*)(&KlL[b][kd]) = sb;
    *(u32x4*)(&VL [b][vd]) = sc;
  };

  bf16x8 qh = *(const bf16x8*)(Qhi + ((size_t)h*SQ + qrow)*HD + g*8);
  bf16x8 ql = *(const bf16x8*)(Qlo + ((size_t)h*SQ + qrow)*HD + g*8);

  f32x4 o0 = {0.f,0.f,0.f,0.f}, o1 = {0.f,0.f,0.f,0.f};
  float m[4], lsum[4];
  #pragma unroll
  for (int r=0;r<4;++r){ m[r] = -3.0e38f; lsum[r] = 0.f; }

  stage_load(kbeg);
  stage_write(0);
  #pragma unroll
  for (int ks=0; ks<4; ++ks) mk_cur[ks] = mk_nxt[ks];
  __syncthreads();
  int cur = 0;

  for (int t=0; t<nkt; ++t){
    // issue next tile's global loads early; consumed by ds_write at tile end
    if (t+1 < nkt) stage_load(kbeg + (t+1)*64);

    // ---- scores S[16q x 64k] from LDS, 3 split terms ----
    f32x4 s[4];
    #pragma unroll
    for (int ks=0; ks<4; ++ks){
      int krow = ks*16 + lm;
      int kidx = (krow*32 + g*8) ^ ((lm&3)<<3);
      bf16x8 kh = *(const bf16x8*)(&KhL[cur][kidx]);
      bf16x8 kl = *(const bf16x8*)(&KlL[cur][kidx]);
      f32x4 a = {0.f,0.f,0.f,0.f};
      __builtin_amdgcn_s_setprio(1);
      a = __builtin_amdgcn_mfma_f32_16x16x32_bf16(qh, kh, a, 0,0,0);
      a = __builtin_amdgcn_mfma_f32_16x16x32_bf16(qh, kl, a, 0,0,0);
      a = __builtin_amdgcn_mfma_f32_16x16x32_bf16(ql, kh, a, 0,0,0);
      __builtin_amdgcn_s_setprio(0);
      float mk = mk_cur[ks];
      #pragma unroll
      for (int r=0;r<4;++r) a[r] += mk;
      s[ks] = a;
    }

    // ---- defer-max with ballot fast path ----
    float tl[4];
    #pragma unroll
    for (int r=0;r<4;++r)
      tl[r] = fmaxf(fmaxf(s[0][r],s[1][r]), fmaxf(s[2][r],s[3][r]));
    bool ok = (tl[0] <= m[0]+8.f) && (tl[1] <= m[1]+8.f) &&
              (tl[2] <= m[2]+8.f) && (tl[3] <= m[3]+8.f);
    if (__ballot(ok) != ~0ULL){
      #pragma unroll
      for (int r=0;r<4;++r){
        float t2 = tl[r];
        #pragma unroll
        for (int off=1; off<16; off<<=1) t2 = fmaxf(t2, __shfl_xor(t2, off));
        float mn = fmaxf(m[r], t2);
        float sc2 = __expf(m[r] - mn);
        o0[r] *= sc2; o1[r] *= sc2; lsum[r] *= sc2;
        m[r] = mn;
      }
    }

    // ---- P = exp(s-m) (bounded e^8), bf16-hi, lane-partial sums ----
    const int prow = w*16 + g*4;
    #pragma unroll
    for (int ks=0; ks<4; ++ks){
      #pragma unroll
      for (int r=0;r<4;++r){
        float p = __expf(s[ks][r] - m[r]);
        lsum[r] += p;
        Ph[prow + r][ks*16 + lm] = bf16_rn(p);
      }
    }

    // ---- PV: ctx += P @ V from LDS ----
    #pragma unroll
    for (int ks2=0; ks2<2; ++ks2){
      bf16x8 pa = *(const bf16x8*)&Ph[w*16 + lm][ks2*32 + g*8];
      int v0i = (lm*64      + ks2*32 + g*8) ^ ((lm&7)<<3);
      int v1i = ((lm+16)*64 + ks2*32 + g*8) ^ ((lm&7)<<3);
      bf16x8 v0 = *(const bf16x8*)(&VL[cur][v0i]);
      bf16x8 v1 = *(const bf16x8*)(&VL[cur][v1i]);
      __builtin_amdgcn_s_setprio(1);
      o0 = __builtin_amdgcn_mfma_f32_16x16x32_bf16(pa, v0, o0, 0,0,0);
      o1 = __builtin_amdgcn_mfma_f32_16x16x32_bf16(pa, v1, o1, 0,0,0);
      __builtin_amdgcn_s_setprio(0);
    }

    // ---- write next tile into the other buffer; one barrier per tile ----
    if (t+1 < nkt){
      stage_write(cur^1);
      #pragma unroll
      for (int ks=0; ks<4; ++ks) mk_cur[ks] = mk_nxt[ks];
    }
    __syncthreads();
    cur ^= 1;
  }

  // ---- final row-sum reduce ----
  float L[4];
  #pragma unroll
  for (int r=0;r<4;++r){
    float t2 = lsum[r];
    #pragma unroll
    for (int off=1; off<16; off<<=1) t2 += __shfl_xor(t2, off);
    L[r] = t2;
  }

  if (direct){
    #pragma unroll
    for (int r=0;r<4;++r){
      float inv = 1.0f / L[r];
      int row = qt*64 + w*16 + g*4 + r;
      opart[(size_t)row*AHS + h*HD + lm]      = o0[r]*inv;
      opart[(size_t)row*AHS + h*HD + 16 + lm] = o1[r]*inv;
    }
  } else {
    #pragma unroll
    for (int r=0;r<4;++r){
      int row = qt*64 + w*16 + g*4 + r;
      opart[((size_t)sp*SQ + row)*AHS + h*HD + lm]      = o0[r];
      opart[((size_t)sp*SQ + row)*AHS + h*HD + 16 + lm] = o1[r];
    }
    if (lm == 0){
      #pragma unroll
      for (int r=0;r<4;++r){
        int row = qt*64 + w*16 + g*4 + r;
        mpart[((size_t)sp*NHEAD + h)*SQ + row] = m[r];
        lpart[((size_t)sp*NHEAD + h)*SQ + row] = L[r];
      }
    }
  }
}

// ---------------- merge partial splits ----------------
__global__ void merge_kernel(const float* __restrict__ opart,
                             const float* __restrict__ mpart,
                             const float* __restrict__ lpart,
                             float* __restrict__ out, int S){
  int idx = blockIdx.x*256 + threadIdx.x;
  if (idx >= SQ*AHS) return;
  int row = idx/AHS, c = idx - row*AHS;
  int h = c >> 5;
  float M = -3.0e38f;
  for (int s=0; s<S; ++s) M = fmaxf(M, mpart[((size_t)s*NHEAD + h)*SQ + row]);
  float num = 0.f, den = 0.f;
  for (int s=0; s<S; ++s){
    float wgt = __expf(mpart[((size_t)s*NHEAD + h)*SQ + row] - M);
    num += wgt * opart[((size_t)s*SQ + row)*AHS + c];
    den += wgt * lpart[((size_t)s*NHEAD + h)*SQ + row];
  }
  out[idx] = num/den;
}

extern "C" void kernel_launch(void* const* d_in, const int* in_sizes, int n_in,
                              void* d_out, int out_size, void* d_ws, size_t ws_size,
                              hipStream_t stream) {
  const float* Xh   = (const float*)d_in[0];
  const float* Xe   = (const float*)d_in[1];
  const float* mask = (const float*)d_in[2];
  const float* Wq   = (const float*)d_in[3];
  const float* bq   = (const float*)d_in[4];
  const float* Wk   = (const float*)d_in[5];
  const float* bk   = (const float*)d_in[6];
  const float* Wv   = (const float*)d_in[7];
  const float* bv   = (const float*)d_in[8];
  float* out = (float*)d_out;

  char* ws = (char*)d_ws;
  size_t off = 0;
  auto alloc = [&](size_t bytes)->void*{
    void* p = ws + off;
    off += (bytes + 255) & ~(size_t)255;
    return p;
  };
  unsigned short* Wthi = (unsigned short*)alloc((size_t)3*DIN*AHS*2);
  unsigned short* Wtlo = (unsigned short*)alloc((size_t)3*DIN*AHS*2);
  unsigned short* Qhi  = (unsigned short*)alloc((size_t)NHEAD*SQ*HD*2);
  unsigned short* Qlo  = (unsigned short*)alloc((size_t)NHEAD*SQ*HD*2);
  unsigned short* Khi  = (unsigned short*)alloc((size_t)NHEAD*SKK*HD*2);
  unsigned short* Klo  = (unsigned short*)alloc((size_t)NHEAD*SKK*HD*2);
  unsigned short* Vt   = (unsigned short*)alloc((size_t)AHS*SKK*2);
  size_t base_end = off;

  const size_t o_bytes  = (size_t)SQ*AHS*4;
  const size_t ml_bytes = (size_t)NHEAD*SQ*4;
  const size_t per_split = ((o_bytes+255)&~(size_t)255) + 2*((ml_bytes+255)&~(size_t)255);

  int S, direct;
  if      (ws_size >= base_end + 4*per_split + 1024) { S = 4; direct = 0; }
  else if (ws_size >= base_end + 2*per_split + 1024) { S = 2; direct = 0; }
  else if (ws_size >= base_end + 1*per_split + 1024) { S = 1; direct = 0; }
  else                                               { S = 1; direct = 1; }

  float *opart, *mpart, *lpart;
  if (!direct){
    opart = (float*)alloc((size_t)S*((o_bytes+255)&~(size_t)255));
    mpart = (float*)alloc((size_t)S*((ml_bytes+255)&~(size_t)255));
    lpart = (float*)alloc((size_t)S*((ml_bytes+255)&~(size_t)255));
  } else {
    opart = out; mpart = (float*)ws; lpart = (float*)ws;
  }

  {
    int tot = 3*DIN*AHS;
    prep_wt_kernel<<<(tot+255)/256, 256, 0, stream>>>(Wq, Wk, Wv, Wthi, Wtlo);
  }
  {
    dim3 grid(SQ/64, AHS/64, 3);
    proj_kernel<<<grid, 256, 0, stream>>>(Xh, Xe, Wthi, Wtlo, bq, bk, bv,
                                          Qhi, Qlo, Khi, Klo, Vt);
  }
  {
    dim3 grid(SQ/64, NHEAD, S);
    int nkt = (SKK/64)/S;
    attn_kernel<<<grid, 256, 0, stream>>>(Qhi, Qlo, Khi, Klo, Vt, mask,
                                          opart, mpart, lpart, nkt, direct);
  }
  if (!direct){
    int n = SQ*AHS;
    merge_kernel<<<(n+255)/256, 256, 0, stream>>>(opart, mpart, lpart, out, S);
  }
}

// Round 4
// 231.444 us; speedup vs baseline: 2.0262x; 1.0141x over previous
//
#include <hip/hip_runtime.h>
#include <hip/hip_bf16.h>

#define SQ 4096
#define SKK 4096
#define DIN 768
#define AHS 384
#define NHEAD 12
#define HD 32

typedef __attribute__((ext_vector_type(8))) short bf16x8;
typedef __attribute__((ext_vector_type(4))) float f32x4;
typedef __attribute__((ext_vector_type(4))) unsigned int u32x4;

__device__ __forceinline__ unsigned short bf16_rn(float x){
  unsigned int u = __float_as_uint(x);
  unsigned int r = u + 0x7fffu + ((u>>16)&1u);
  return (unsigned short)(r>>16);
}
__device__ __forceinline__ float bf16_f(unsigned short h){
  return __uint_as_float(((unsigned int)h)<<16);
}

// ---------------- prep: W -> W^T split into bf16 hi/lo ----------------
__global__ void prep_wt_kernel(const float* __restrict__ Wq, const float* __restrict__ Wk,
                               const float* __restrict__ Wv,
                               unsigned short* __restrict__ Wthi, unsigned short* __restrict__ Wtlo){
  int idx = blockIdx.x*256 + threadIdx.x;
  const int per = DIN*AHS;
  if (idx >= 3*per) return;
  int mat = idx/per, rem = idx - mat*per;
  int k = rem/AHS, n = rem - k*AHS;
  const float* W = (mat==0)?Wq:((mat==1)?Wk:Wv);
  float v = W[k*AHS+n];
  unsigned short hh = bf16_rn(v);
  unsigned short ll = bf16_rn(v - bf16_f(hh));
  Wthi[mat*per + n*DIN + k] = hh;
  Wtlo[mat*per + n*DIN + k] = ll;
}

// ---------------- split X (fp32) -> bf16 hi/lo, 8 elems/thread ----------------
__global__ void split_x_kernel(const float* __restrict__ Xh, const float* __restrict__ Xe,
                               unsigned short* __restrict__ Xhh, unsigned short* __restrict__ Xhl,
                               unsigned short* __restrict__ Xeh, unsigned short* __restrict__ Xel){
  const int n8 = (SQ*DIN)/8;
  int t = blockIdx.x*256 + threadIdx.x;
  const float* src; unsigned short *dh, *dl; int i;
  if (t < n8){ src = Xh; dh = Xhh; dl = Xhl; i = t; }
  else       { src = Xe; dh = Xeh; dl = Xel; i = t - n8; }
  f32x4 x0 = *(const f32x4*)(src + (size_t)i*8);
  f32x4 x1 = *(const f32x4*)(src + (size_t)i*8 + 4);
  bf16x8 hi, lo;
  #pragma unroll
  for (int j=0;j<4;++j){
    unsigned short h0 = bf16_rn(x0[j]);
    hi[j]   = (short)h0; lo[j]   = (short)bf16_rn(x0[j] - bf16_f(h0));
    unsigned short h1 = bf16_rn(x1[j]);
    hi[4+j] = (short)h1; lo[4+j] = (short)bf16_rn(x1[j] - bf16_f(h1));
  }
  *(bf16x8*)(dh + (size_t)i*8) = hi;
  *(bf16x8*)(dl + (size_t)i*8) = lo;
}

// ---------------- QKV projection GEMM (64x64 tiles) ----------------
// z=0: Q (scaled 1/sqrt(32)) hi/lo HEAD-MAJOR [H][SQ][HD]
// z=1: K hi/lo HEAD-MAJOR [H][SKK][HD]
// z=2: V bf16 hi-only, TRANSPOSED [AHS][SKK]
// PRESPLIT=1: A operands from pre-split bf16 Xhh/Xhl/Xeh/Xel with reg pipeline.
// PRESPLIT=0: fallback, converts fp32 X in-kernel (round-3 path).
template<int PRESPLIT>
__global__ __launch_bounds__(256,4) void proj_kernel(
    const float* __restrict__ Xh, const float* __restrict__ Xe,
    const unsigned short* __restrict__ Xhh, const unsigned short* __restrict__ Xhl,
    const unsigned short* __restrict__ Xeh, const unsigned short* __restrict__ Xel,
    const unsigned short* __restrict__ Wthi, const unsigned short* __restrict__ Wtlo,
    const float* __restrict__ bq, const float* __restrict__ bk, const float* __restrict__ bv,
    unsigned short* __restrict__ Qhi, unsigned short* __restrict__ Qlo,
    unsigned short* __restrict__ Khi, unsigned short* __restrict__ Klo,
    unsigned short* __restrict__ Vt)
{
  const int z = blockIdx.z;
  const float* bias = (z==0) ? bq : ((z==1) ? bk : bv);
  const unsigned short* Wh = Wthi + (size_t)z*(DIN*AHS);
  const unsigned short* Wl = Wtlo + (size_t)z*(DIN*AHS);

  const int m0 = blockIdx.x*64;
  const int n0 = blockIdx.y*64;
  const int w  = threadIdx.x>>6, lane = threadIdx.x&63;
  const int lm = lane&15, g = lane>>4;
  const int wm = w>>1, wn = w&1;     // 2x2 waves, wave tile 32x32

  f32x4 acc[2][2];
  for (int mi=0;mi<2;++mi) for (int ni=0;ni<2;++ni) acc[mi][ni] = (f32x4){0.f,0.f,0.f,0.f};

  if constexpr (PRESPLIT){
    const unsigned short* Ah = (z==0) ? Xhh : Xeh;
    const unsigned short* Al = (z==0) ? Xhl : Xel;
    const unsigned short* pa0 = Ah + (size_t)(m0+wm*32+lm)*DIN + g*8;
    const unsigned short* pa1 = pa0 + 16*DIN;
    const unsigned short* la0 = Al + (size_t)(m0+wm*32+lm)*DIN + g*8;
    const unsigned short* la1 = la0 + 16*DIN;
    const unsigned short* pb0 = Wh + (size_t)(n0+wn*32+lm)*DIN + g*8;
    const unsigned short* pb1 = pb0 + 16*DIN;
    const unsigned short* lb0 = Wl + (size_t)(n0+wn*32+lm)*DIN + g*8;
    const unsigned short* lb1 = lb0 + 16*DIN;

    bf16x8 cah0 = *(const bf16x8*)pa0, cah1 = *(const bf16x8*)pa1;
    bf16x8 cbh0 = *(const bf16x8*)pb0, cbh1 = *(const bf16x8*)pb1;
    bf16x8 cal0, cal1, cbl0, cbl1;
    if (z != 2){
      cal0 = *(const bf16x8*)la0; cal1 = *(const bf16x8*)la1;
      cbl0 = *(const bf16x8*)lb0; cbl1 = *(const bf16x8*)lb1;
    }

    for (int kk=0; kk<DIN; kk+=32){
      bf16x8 nah0, nah1, nbh0, nbh1, nal0, nal1, nbl0, nbl1;
      const bool more = (kk+32 < DIN);
      if (more){
        nah0 = *(const bf16x8*)(pa0 + kk+32); nah1 = *(const bf16x8*)(pa1 + kk+32);
        nbh0 = *(const bf16x8*)(pb0 + kk+32); nbh1 = *(const bf16x8*)(pb1 + kk+32);
        if (z != 2){
          nal0 = *(const bf16x8*)(la0 + kk+32); nal1 = *(const bf16x8*)(la1 + kk+32);
          nbl0 = *(const bf16x8*)(lb0 + kk+32); nbl1 = *(const bf16x8*)(lb1 + kk+32);
        }
      }
      __builtin_amdgcn_s_setprio(1);
      acc[0][0] = __builtin_amdgcn_mfma_f32_16x16x32_bf16(cah0, cbh0, acc[0][0], 0,0,0);
      acc[1][0] = __builtin_amdgcn_mfma_f32_16x16x32_bf16(cah1, cbh0, acc[1][0], 0,0,0);
      acc[0][1] = __builtin_amdgcn_mfma_f32_16x16x32_bf16(cah0, cbh1, acc[0][1], 0,0,0);
      acc[1][1] = __builtin_amdgcn_mfma_f32_16x16x32_bf16(cah1, cbh1, acc[1][1], 0,0,0);
      if (z != 2){
        acc[0][0] = __builtin_amdgcn_mfma_f32_16x16x32_bf16(cah0, cbl0, acc[0][0], 0,0,0);
        acc[1][0] = __builtin_amdgcn_mfma_f32_16x16x32_bf16(cah1, cbl0, acc[1][0], 0,0,0);
        acc[0][1] = __builtin_amdgcn_mfma_f32_16x16x32_bf16(cah0, cbl1, acc[0][1], 0,0,0);
        acc[1][1] = __builtin_amdgcn_mfma_f32_16x16x32_bf16(cah1, cbl1, acc[1][1], 0,0,0);
        acc[0][0] = __builtin_amdgcn_mfma_f32_16x16x32_bf16(cal0, cbh0, acc[0][0], 0,0,0);
        acc[1][0] = __builtin_amdgcn_mfma_f32_16x16x32_bf16(cal1, cbh0, acc[1][0], 0,0,0);
        acc[0][1] = __builtin_amdgcn_mfma_f32_16x16x32_bf16(cal0, cbh1, acc[0][1], 0,0,0);
        acc[1][1] = __builtin_amdgcn_mfma_f32_16x16x32_bf16(cal1, cbh1, acc[1][1], 0,0,0);
      }
      __builtin_amdgcn_s_setprio(0);
      if (more){
        cah0=nah0; cah1=nah1; cbh0=nbh0; cbh1=nbh1;
        if (z != 2){ cal0=nal0; cal1=nal1; cbl0=nbl0; cbl1=nbl1; }
      }
    }
  } else {
    const float* X = (z==0) ? Xh : Xe;
    for (int kk=0; kk<DIN; kk+=32){
      bf16x8 ahf[2], alf[2];
      for (int mi=0; mi<2; ++mi){
        int row = m0 + wm*32 + mi*16 + lm;
        const float* xp = X + (size_t)row*DIN + kk + g*8;
        f32x4 x0 = *(const f32x4*)(xp);
        f32x4 x1 = *(const f32x4*)(xp+4);
        bf16x8 ah, al;
        #pragma unroll
        for (int i=0;i<4;i++){
          unsigned short h0 = bf16_rn(x0[i]);
          ah[i] = (short)h0; al[i] = (short)bf16_rn(x0[i] - bf16_f(h0));
          unsigned short h1 = bf16_rn(x1[i]);
          ah[4+i] = (short)h1; al[4+i] = (short)bf16_rn(x1[i] - bf16_f(h1));
        }
        ahf[mi]=ah; alf[mi]=al;
      }
      #pragma unroll
      for (int ni=0; ni<2; ++ni){
        int col = n0 + wn*32 + ni*16 + lm;
        bf16x8 bh = *(const bf16x8*)(Wh + (size_t)col*DIN + kk + g*8);
        bf16x8 bl = *(const bf16x8*)(Wl + (size_t)col*DIN + kk + g*8);
        #pragma unroll
        for (int mi=0; mi<2; ++mi){
          acc[mi][ni] = __builtin_amdgcn_mfma_f32_16x16x32_bf16(ahf[mi], bh, acc[mi][ni], 0,0,0);
          if (z != 2){
            acc[mi][ni] = __builtin_amdgcn_mfma_f32_16x16x32_bf16(ahf[mi], bl, acc[mi][ni], 0,0,0);
            acc[mi][ni] = __builtin_amdgcn_mfma_f32_16x16x32_bf16(alf[mi], bh, acc[mi][ni], 0,0,0);
          }
        }
      }
    }
  }

  const float qscale = 0.17677669529663687f; // 1/sqrt(32)
  for (int ni=0; ni<2; ++ni){
    int col = n0 + wn*32 + ni*16 + lm;
    float bcol = bias[col];
    int hq = col>>5, d = col&31;
    for (int mi=0; mi<2; ++mi){
      #pragma unroll
      for (int r=0; r<4; ++r){
        int row = m0 + wm*32 + mi*16 + g*4 + r;
        float v = acc[mi][ni][r] + bcol;
        if (z==0) v *= qscale;
        unsigned short hh = bf16_rn(v);
        if (z==0)      { unsigned short ll = bf16_rn(v - bf16_f(hh));
                         size_t p = ((size_t)hq*SQ + row)*HD + d;
                         Qhi[p]=hh; Qlo[p]=ll; }
        else if (z==1) { unsigned short ll = bf16_rn(v - bf16_f(hh));
                         size_t p = ((size_t)hq*SKK + row)*HD + d;
                         Khi[p]=hh; Klo[p]=ll; }
        else           { Vt[(size_t)col*SKK+row]=hh; }
      }
    }
  }
}

// ---------------- fused flash attention, split-K, LDS-staged K/V ----------------
__global__ __launch_bounds__(256) void attn_kernel(
    const unsigned short* __restrict__ Qhi, const unsigned short* __restrict__ Qlo,
    const unsigned short* __restrict__ Khi, const unsigned short* __restrict__ Klo,
    const unsigned short* __restrict__ Vt,
    const float* __restrict__ mask,
    float* __restrict__ opart, float* __restrict__ mpart, float* __restrict__ lpart,
    int nkt, int direct)
{
  const int qt = blockIdx.x, h = blockIdx.y, sp = blockIdx.z;
  const int tid = threadIdx.x;
  const int w = tid>>6, lane = tid&63;
  const int lm = lane&15, g = lane>>4;
  const int qrow = qt*64 + w*16 + lm;
  const int kbeg = sp*nkt*64;

  __shared__ unsigned short KhL[2][2048];
  __shared__ unsigned short KlL[2][2048];
  __shared__ unsigned short VL [2][2048];
  __shared__ unsigned short Ph[64][72];

  const unsigned short* Khg = Khi + (size_t)h*SKK*HD;
  const unsigned short* Klg = Klo + (size_t)h*SKK*HD;

  const int krow_s = tid>>2, kcol_s = (tid&3)*8;
  const int vrow_s = tid>>3, vcol_s = (tid&7)*8;
  const int kd = (tid*8) ^ (((tid>>2)&3)<<3);
  const int vd = (tid*8) ^ (((tid>>3)&7)<<3);

  u32x4 sa, sb, sc;
  float mk_nxt[4], mk_cur[4];
  auto stage_load = [&](int kb){
    sa = *(const u32x4*)(Khg + (size_t)(kb + krow_s)*HD + kcol_s);
    sb = *(const u32x4*)(Klg + (size_t)(kb + krow_s)*HD + kcol_s);
    sc = *(const u32x4*)(Vt + (size_t)(h*HD + vrow_s)*SKK + kb + vcol_s);
    #pragma unroll
    for (int ks=0; ks<4; ++ks) mk_nxt[ks] = mask[kb + ks*16 + lm];
  };
  auto stage_write = [&](int b){
    *(u32x4*)(&KhL[b][kd]) = sa;
    *(u32x4*)(&KlL[b][kd]) = sb;
    *(u32x4*)(&VL [b][vd]) = sc;
  };

  bf16x8 qh = *(const bf16x8*)(Qhi + ((size_t)h*SQ + qrow)*HD + g*8);
  bf16x8 ql = *(const bf16x8*)(Qlo + ((size_t)h*SQ + qrow)*HD + g*8);

  f32x4 o0 = {0.f,0.f,0.f,0.f}, o1 = {0.f,0.f,0.f,0.f};
  float m[4], lsum[4];
  #pragma unroll
  for (int r=0;r<4;++r){ m[r] = -3.0e38f; lsum[r] = 0.f; }

  stage_load(kbeg);
  stage_write(0);
  #pragma unroll
  for (int ks=0; ks<4; ++ks) mk_cur[ks] = mk_nxt[ks];
  __syncthreads();
  int cur = 0;

  for (int t=0; t<nkt; ++t){
    if (t+1 < nkt) stage_load(kbeg + (t+1)*64);

    f32x4 s[4];
    #pragma unroll
    for (int ks=0; ks<4; ++ks){
      int krow = ks*16 + lm;
      int kidx = (krow*32 + g*8) ^ ((lm&3)<<3);
      bf16x8 kh = *(const bf16x8*)(&KhL[cur][kidx]);
      bf16x8 kl = *(const bf16x8*)(&KlL[cur][kidx]);
      f32x4 a = {0.f,0.f,0.f,0.f};
      __builtin_amdgcn_s_setprio(1);
      a = __builtin_amdgcn_mfma_f32_16x16x32_bf16(qh, kh, a, 0,0,0);
      a = __builtin_amdgcn_mfma_f32_16x16x32_bf16(qh, kl, a, 0,0,0);
      a = __builtin_amdgcn_mfma_f32_16x16x32_bf16(ql, kh, a, 0,0,0);
      __builtin_amdgcn_s_setprio(0);
      float mk = mk_cur[ks];
      #pragma unroll
      for (int r=0;r<4;++r) a[r] += mk;
      s[ks] = a;
    }

    float tl[4];
    #pragma unroll
    for (int r=0;r<4;++r)
      tl[r] = fmaxf(fmaxf(s[0][r],s[1][r]), fmaxf(s[2][r],s[3][r]));
    bool ok = (tl[0] <= m[0]+8.f) && (tl[1] <= m[1]+8.f) &&
              (tl[2] <= m[2]+8.f) && (tl[3] <= m[3]+8.f);
    if (__ballot(ok) != ~0ULL){
      #pragma unroll
      for (int r=0;r<4;++r){
        float t2 = tl[r];
        #pragma unroll
        for (int off=1; off<16; off<<=1) t2 = fmaxf(t2, __shfl_xor(t2, off));
        float mn = fmaxf(m[r], t2);
        float sc2 = __expf(m[r] - mn);
        o0[r] *= sc2; o1[r] *= sc2; lsum[r] *= sc2;
        m[r] = mn;
      }
    }

    const int prow = w*16 + g*4;
    #pragma unroll
    for (int ks=0; ks<4; ++ks){
      #pragma unroll
      for (int r=0;r<4;++r){
        float p = __expf(s[ks][r] - m[r]);
        lsum[r] += p;
        Ph[prow + r][ks*16 + lm] = bf16_rn(p);
      }
    }

    #pragma unroll
    for (int ks2=0; ks2<2; ++ks2){
      bf16x8 pa = *(const bf16x8*)&Ph[w*16 + lm][ks2*32 + g*8];
      int v0i = (lm*64      + ks2*32 + g*8) ^ ((lm&7)<<3);
      int v1i = ((lm+16)*64 + ks2*32 + g*8) ^ ((lm&7)<<3);
      bf16x8 v0 = *(const bf16x8*)(&VL[cur][v0i]);
      bf16x8 v1 = *(const bf16x8*)(&VL[cur][v1i]);
      __builtin_amdgcn_s_setprio(1);
      o0 = __builtin_amdgcn_mfma_f32_16x16x32_bf16(pa, v0, o0, 0,0,0);
      o1 = __builtin_amdgcn_mfma_f32_16x16x32_bf16(pa, v1, o1, 0,0,0);
      __builtin_amdgcn_s_setprio(0);
    }

    if (t+1 < nkt){
      stage_write(cur^1);
      #pragma unroll
      for (int ks=0; ks<4; ++ks) mk_cur[ks] = mk_nxt[ks];
    }
    __syncthreads();
    cur ^= 1;
  }

  float L[4];
  #pragma unroll
  for (int r=0;r<4;++r){
    float t2 = lsum[r];
    #pragma unroll
    for (int off=1; off<16; off<<=1) t2 += __shfl_xor(t2, off);
    L[r] = t2;
  }

  if (direct){
    #pragma unroll
    for (int r=0;r<4;++r){
      float inv = 1.0f / L[r];
      int row = qt*64 + w*16 + g*4 + r;
      opart[(size_t)row*AHS + h*HD + lm]      = o0[r]*inv;
      opart[(size_t)row*AHS + h*HD + 16 + lm] = o1[r]*inv;
    }
  } else {
    #pragma unroll
    for (int r=0;r<4;++r){
      int row = qt*64 + w*16 + g*4 + r;
      opart[((size_t)sp*SQ + row)*AHS + h*HD + lm]      = o0[r];
      opart[((size_t)sp*SQ + row)*AHS + h*HD + 16 + lm] = o1[r];
    }
    if (lm == 0){
      #pragma unroll
      for (int r=0;r<4;++r){
        int row = qt*64 + w*16 + g*4 + r;
        mpart[((size_t)sp*NHEAD + h)*SQ + row] = m[r];
        lpart[((size_t)sp*NHEAD + h)*SQ + row] = L[r];
      }
    }
  }
}

// ---------------- merge partial splits ----------------
__global__ void merge_kernel(const float* __restrict__ opart,
                             const float* __restrict__ mpart,
                             const float* __restrict__ lpart,
                             float* __restrict__ out, int S){
  int idx = blockIdx.x*256 + threadIdx.x;
  if (idx >= SQ*AHS) return;
  int row = idx/AHS, c = idx - row*AHS;
  int h = c >> 5;
  float M = -3.0e38f;
  for (int s=0; s<S; ++s) M = fmaxf(M, mpart[((size_t)s*NHEAD + h)*SQ + row]);
  float num = 0.f, den = 0.f;
  for (int s=0; s<S; ++s){
    float wgt = __expf(mpart[((size_t)s*NHEAD + h)*SQ + row] - M);
    num += wgt * opart[((size_t)s*SQ + row)*AHS + c];
    den += wgt * lpart[((size_t)s*NHEAD + h)*SQ + row];
  }
  out[idx] = num/den;
}

extern "C" void kernel_launch(void* const* d_in, const int* in_sizes, int n_in,
                              void* d_out, int out_size, void* d_ws, size_t ws_size,
                              hipStream_t stream) {
  const float* Xh   = (const float*)d_in[0];
  const float* Xe   = (const float*)d_in[1];
  const float* mask = (const float*)d_in[2];
  const float* Wq   = (const float*)d_in[3];
  const float* bq   = (const float*)d_in[4];
  const float* Wk   = (const float*)d_in[5];
  const float* bk   = (const float*)d_in[6];
  const float* Wv   = (const float*)d_in[7];
  const float* bv   = (const float*)d_in[8];
  float* out = (float*)d_out;

  char* ws = (char*)d_ws;
  auto al256 = [](size_t b)->size_t{ return (b + 255) & ~(size_t)255; };
  size_t off = 0;
  auto alloc = [&](size_t bytes)->void*{ void* p = ws + off; off += al256(bytes); return p; };

  unsigned short* Wthi = (unsigned short*)alloc((size_t)3*DIN*AHS*2);
  unsigned short* Wtlo = (unsigned short*)alloc((size_t)3*DIN*AHS*2);
  unsigned short* Qhi  = (unsigned short*)alloc((size_t)NHEAD*SQ*HD*2);
  unsigned short* Qlo  = (unsigned short*)alloc((size_t)NHEAD*SQ*HD*2);
  unsigned short* Khi  = (unsigned short*)alloc((size_t)NHEAD*SKK*HD*2);
  unsigned short* Klo  = (unsigned short*)alloc((size_t)NHEAD*SKK*HD*2);
  unsigned short* Vt   = (unsigned short*)alloc((size_t)AHS*SKK*2);
  const size_t base_end = off;

  const size_t XB = al256((size_t)SQ*DIN*2);       // one bf16 X buffer
  const size_t OB = al256((size_t)SQ*AHS*4);       // one opart split
  const size_t MB = al256((size_t)NHEAD*SQ*4);     // one m/l split
  const size_t xneed = 4*XB;

  auto fits = [&](int S, int presplit)->bool{
    size_t need_u = (size_t)S*OB + 2*(size_t)S*MB;
    if (presplit && xneed > need_u) need_u = xneed;
    return base_end + need_u + 1024 <= ws_size;
  };

  int presplit = 1, S = 1, direct = 0;
  if      (fits(8,1)) S = 8;
  else if (fits(4,1)) S = 4;
  else if (fits(2,1)) S = 2;
  else if (fits(1,1)) S = 1;
  else {
    presplit = 0;
    if      (fits(4,0)) S = 4;
    else if (fits(2,0)) S = 2;
    else if (fits(1,0)) S = 1;
    else { S = 1; direct = 1; }
  }

  char* ureg = ws + base_end;
  unsigned short* Xhh = (unsigned short*)(ureg);
  unsigned short* Xhl = (unsigned short*)(ureg + XB);
  unsigned short* Xeh = (unsigned short*)(ureg + 2*XB);
  unsigned short* Xel = (unsigned short*)(ureg + 3*XB);

  float *opart, *mpart, *lpart;
  if (!direct){
    opart = (float*)(ureg);                       // aliases X-split region (disjoint lifetimes)
    mpart = (float*)(ureg + (size_t)S*OB);
    lpart = (float*)(ureg + (size_t)S*OB + (size_t)S*MB);
  } else {
    opart = out; mpart = (float*)ws; lpart = (float*)ws;
  }

  {
    int tot = 3*DIN*AHS;
    prep_wt_kernel<<<(tot+255)/256, 256, 0, stream>>>(Wq, Wk, Wv, Wthi, Wtlo);
  }
  if (presplit){
    int nthr = 2*(SQ*DIN)/8;
    split_x_kernel<<<nthr/256, 256, 0, stream>>>(Xh, Xe, Xhh, Xhl, Xeh, Xel);
  }
  {
    dim3 grid(SQ/64, AHS/64, 3);
    if (presplit)
      proj_kernel<1><<<grid, 256, 0, stream>>>(Xh, Xe, Xhh, Xhl, Xeh, Xel,
                                               Wthi, Wtlo, bq, bk, bv,
                                               Qhi, Qlo, Khi, Klo, Vt);
    else
      proj_kernel<0><<<grid, 256, 0, stream>>>(Xh, Xe, Xhh, Xhl, Xeh, Xel,
                                               Wthi, Wtlo, bq, bk, bv,
                                               Qhi, Qlo, Khi, Klo, Vt);
  }
  {
    dim3 grid(SQ/64, NHEAD, S);
    int nkt = (SKK/64)/S;
    attn_kernel<<<grid, 256, 0, stream>>>(Qhi, Qlo, Khi, Klo, Vt, mask,
                                          opart, mpart, lpart, nkt, direct);
  }
  if (!direct){
    int n = SQ*AHS;
    merge_kernel<<<(n+255)/256, 256, 0, stream>>>(opart, mpart, lpart, out, S);
  }
}

// Round 5
// 194.044 us; speedup vs baseline: 2.4167x; 1.1927x over previous
//
#include <hip/hip_runtime.h>
#include <hip/hip_bf16.h>

#define SQ 4096
#define SKK 4096
#define DIN 768
#define AHS 384
#define NHEAD 12
#define HD 32

typedef __attribute__((ext_vector_type(8))) short bf16x8;
typedef __attribute__((ext_vector_type(4))) float f32x4;
typedef __attribute__((ext_vector_type(4))) unsigned int u32x4;

#define LOG2E 1.4426950408889634f
// log2(e)/sqrt(32): folds both the 1/sqrt(d) score scale and the exp->exp2
// domain change into the Q projection.
#define QSCALE 0.25503486168652855f

__device__ __forceinline__ unsigned short bf16_rn(float x){
  unsigned int u = __float_as_uint(x);
  unsigned int r = u + 0x7fffu + ((u>>16)&1u);
  return (unsigned short)(r>>16);
}
__device__ __forceinline__ float bf16_f(unsigned short h){
  return __uint_as_float(((unsigned int)h)<<16);
}

// ---------------- prep: W -> W^T split into bf16 hi/lo ----------------
__global__ void prep_wt_kernel(const float* __restrict__ Wq, const float* __restrict__ Wk,
                               const float* __restrict__ Wv,
                               unsigned short* __restrict__ Wthi, unsigned short* __restrict__ Wtlo){
  int idx = blockIdx.x*256 + threadIdx.x;
  const int per = DIN*AHS;
  if (idx >= 3*per) return;
  int mat = idx/per, rem = idx - mat*per;
  int k = rem/AHS, n = rem - k*AHS;
  const float* W = (mat==0)?Wq:((mat==1)?Wk:Wv);
  float v = W[k*AHS+n];
  unsigned short hh = bf16_rn(v);
  unsigned short ll = bf16_rn(v - bf16_f(hh));
  Wthi[mat*per + n*DIN + k] = hh;
  Wtlo[mat*per + n*DIN + k] = ll;
}

// ---------------- split X (fp32) -> bf16 hi/lo, 8 elems/thread ----------------
__global__ void split_x_kernel(const float* __restrict__ Xh, const float* __restrict__ Xe,
                               unsigned short* __restrict__ Xhh, unsigned short* __restrict__ Xhl,
                               unsigned short* __restrict__ Xeh, unsigned short* __restrict__ Xel){
  const int n8 = (SQ*DIN)/8;
  int t = blockIdx.x*256 + threadIdx.x;
  const float* src; unsigned short *dh, *dl; int i;
  if (t < n8){ src = Xh; dh = Xhh; dl = Xhl; i = t; }
  else       { src = Xe; dh = Xeh; dl = Xel; i = t - n8; }
  f32x4 x0 = *(const f32x4*)(src + (size_t)i*8);
  f32x4 x1 = *(const f32x4*)(src + (size_t)i*8 + 4);
  bf16x8 hi, lo;
  #pragma unroll
  for (int j=0;j<4;++j){
    unsigned short h0 = bf16_rn(x0[j]);
    hi[j]   = (short)h0; lo[j]   = (short)bf16_rn(x0[j] - bf16_f(h0));
    unsigned short h1 = bf16_rn(x1[j]);
    hi[4+j] = (short)h1; lo[4+j] = (short)bf16_rn(x1[j] - bf16_f(h1));
  }
  *(bf16x8*)(dh + (size_t)i*8) = hi;
  *(bf16x8*)(dl + (size_t)i*8) = lo;
}

// ---------------- proj2: 128x128 tile, 8 waves, LDS double-buffered ----------------
// z=0: Q (scaled log2e/sqrt32) hi/lo HEAD-MAJOR [H][SQ][HD]
// z=1: K hi/lo HEAD-MAJOR [H][SKK][HD]
// z=2: V bf16 hi-only, TRANSPOSED [AHS][SKK] (written via LDS transpose)
__global__ __launch_bounds__(512,4) void proj2_kernel(
    const unsigned short* __restrict__ Xhh, const unsigned short* __restrict__ Xhl,
    const unsigned short* __restrict__ Xeh, const unsigned short* __restrict__ Xel,
    const unsigned short* __restrict__ Wthi, const unsigned short* __restrict__ Wtlo,
    const float* __restrict__ bq, const float* __restrict__ bk, const float* __restrict__ bv,
    unsigned short* __restrict__ Qhi, unsigned short* __restrict__ Qlo,
    unsigned short* __restrict__ Khi, unsigned short* __restrict__ Klo,
    unsigned short* __restrict__ Vt)
{
  const int z = blockIdx.z;
  const unsigned short* Ah = (z==0) ? Xhh : Xeh;
  const unsigned short* Al = (z==0) ? Xhl : Xel;
  const unsigned short* Bh = Wthi + (size_t)z*(DIN*AHS);
  const unsigned short* Bl = Wtlo + (size_t)z*(DIN*AHS);
  const float* bias = (z==0) ? bq : ((z==1) ? bk : bv);

  const int m0 = blockIdx.x*128;
  const int n0 = blockIdx.y*128;
  const int tid = threadIdx.x;
  const int w = tid>>6, lane = tid&63;
  const int lm = lane&15, g = lane>>4;
  const int wm = w>>1, wn = w&1;   // 4m x 2n waves, wave tile 32x64

  // SH layout: [buf(2)][sel(4)][4096 shorts]; sel 0=Ah 1=Al 2=Bh 3=Bl. 64KB total.
  __shared__ __align__(16) unsigned short SH[32768];

  const int srow = tid>>2, scol = (tid&3)*8;
  const size_t ga = (size_t)(m0 + srow)*DIN + scol;
  const size_t gb = (size_t)(n0 + srow)*DIN + scol;
  const int sidx = srow*32 + scol;

  u32x4 ra, rla, rb, rlb;
  auto sload = [&](int kk){
    ra = *(const u32x4*)(Ah + ga + kk);
    rb = *(const u32x4*)(Bh + gb + kk);
    if (z != 2){
      rla = *(const u32x4*)(Al + ga + kk);
      rlb = *(const u32x4*)(Bl + gb + kk);
    }
  };
  auto swrite = [&](int b){
    *(u32x4*)&SH[b*16384 + 0*4096 + sidx] = ra;
    *(u32x4*)&SH[b*16384 + 2*4096 + sidx] = rb;
    if (z != 2){
      *(u32x4*)&SH[b*16384 + 1*4096 + sidx] = rla;
      *(u32x4*)&SH[b*16384 + 3*4096 + sidx] = rlb;
    }
  };

  f32x4 acc[2][4];
  #pragma unroll
  for (int mi=0;mi<2;++mi)
    #pragma unroll
    for (int ni=0;ni<4;++ni) acc[mi][ni] = (f32x4){0.f,0.f,0.f,0.f};

  sload(0); swrite(0); __syncthreads();
  int cur = 0;

  const int NKS = DIN/32;  // 24
  for (int t=0; t<NKS; ++t){
    if (t+1 < NKS) sload((t+1)*32);

    const unsigned short* AhL = &SH[cur*16384 + 0*4096];
    const unsigned short* AlL = &SH[cur*16384 + 1*4096];
    const unsigned short* BhL = &SH[cur*16384 + 2*4096];
    const unsigned short* BlL = &SH[cur*16384 + 3*4096];

    bf16x8 a0h = *(const bf16x8*)&AhL[(wm*32 + lm)*32 + g*8];
    bf16x8 a1h = *(const bf16x8*)&AhL[(wm*32 + 16 + lm)*32 + g*8];
    bf16x8 a0l, a1l;
    if (z != 2){
      a0l = *(const bf16x8*)&AlL[(wm*32 + lm)*32 + g*8];
      a1l = *(const bf16x8*)&AlL[(wm*32 + 16 + lm)*32 + g*8];
    }
    __builtin_amdgcn_s_setprio(1);
    #pragma unroll
    for (int ni=0; ni<4; ++ni){
      bf16x8 bh = *(const bf16x8*)&BhL[(wn*64 + ni*16 + lm)*32 + g*8];
      acc[0][ni] = __builtin_amdgcn_mfma_f32_16x16x32_bf16(a0h, bh, acc[0][ni], 0,0,0);
      acc[1][ni] = __builtin_amdgcn_mfma_f32_16x16x32_bf16(a1h, bh, acc[1][ni], 0,0,0);
      if (z != 2){
        bf16x8 bl = *(const bf16x8*)&BlL[(wn*64 + ni*16 + lm)*32 + g*8];
        acc[0][ni] = __builtin_amdgcn_mfma_f32_16x16x32_bf16(a0h, bl, acc[0][ni], 0,0,0);
        acc[1][ni] = __builtin_amdgcn_mfma_f32_16x16x32_bf16(a1h, bl, acc[1][ni], 0,0,0);
        acc[0][ni] = __builtin_amdgcn_mfma_f32_16x16x32_bf16(a0l, bh, acc[0][ni], 0,0,0);
        acc[1][ni] = __builtin_amdgcn_mfma_f32_16x16x32_bf16(a1l, bh, acc[1][ni], 0,0,0);
      }
    }
    __builtin_amdgcn_s_setprio(0);

    if (t+1 < NKS) swrite(cur^1);
    __syncthreads();
    cur ^= 1;
  }

  if (z != 2){
    #pragma unroll
    for (int ni=0; ni<4; ++ni){
      int col = n0 + wn*64 + ni*16 + lm;
      float bcol = bias[col];
      int hq = col>>5, d = col&31;
      #pragma unroll
      for (int mi=0; mi<2; ++mi){
        #pragma unroll
        for (int r=0; r<4; ++r){
          int row = m0 + wm*32 + mi*16 + g*4 + r;
          float v = acc[mi][ni][r] + bcol;
          if (z==0) v *= QSCALE;
          unsigned short hh = bf16_rn(v);
          unsigned short ll = bf16_rn(v - bf16_f(hh));
          size_t p = (z==0) ? ((size_t)hq*SQ + row)*HD + d
                            : ((size_t)hq*SKK + row)*HD + d;
          if (z==0){ Qhi[p]=hh; Qlo[p]=ll; } else { Khi[p]=hh; Klo[p]=ll; }
        }
      }
    }
  } else {
    // V: LDS transpose then coalesced 16B writes. Tile [128col][128row] swizzled.
    #pragma unroll
    for (int ni=0; ni<4; ++ni){
      int lcol = wn*64 + ni*16 + lm;
      float bcol = bias[n0 + lcol];
      #pragma unroll
      for (int mi=0; mi<2; ++mi){
        #pragma unroll
        for (int r=0; r<4; ++r){
          int lrow = wm*32 + mi*16 + g*4 + r;
          SH[lcol*128 + (lrow ^ ((lcol&7)<<3))] = bf16_rn(acc[mi][ni][r] + bcol);
        }
      }
    }
    __syncthreads();
    #pragma unroll
    for (int p=0; p<4; ++p){
      int c = tid>>2, rc = (tid&3)*8 + p*32;
      bf16x8 vv = *(const bf16x8*)&SH[c*128 + (rc ^ ((c&7)<<3))];
      *(bf16x8*)(Vt + (size_t)(n0 + c)*SKK + m0 + rc) = vv;
    }
  }
}

// ---------------- fallback proj (low-ws): fp32 X converted in-kernel ----------------
__global__ __launch_bounds__(256) void proj_fallback_kernel(
    const float* __restrict__ Xh, const float* __restrict__ Xe,
    const unsigned short* __restrict__ Wthi, const unsigned short* __restrict__ Wtlo,
    const float* __restrict__ bq, const float* __restrict__ bk, const float* __restrict__ bv,
    unsigned short* __restrict__ Qhi, unsigned short* __restrict__ Qlo,
    unsigned short* __restrict__ Khi, unsigned short* __restrict__ Klo,
    unsigned short* __restrict__ Vt)
{
  const int z = blockIdx.z;
  const float* X    = (z==0) ? Xh : Xe;
  const float* bias = (z==0) ? bq : ((z==1) ? bk : bv);
  const unsigned short* Wh = Wthi + (size_t)z*(DIN*AHS);
  const unsigned short* Wl = Wtlo + (size_t)z*(DIN*AHS);

  const int m0 = blockIdx.x*64;
  const int n0 = blockIdx.y*64;
  const int w  = threadIdx.x>>6, lane = threadIdx.x&63;
  const int lm = lane&15, g = lane>>4;
  const int wm = w>>1, wn = w&1;

  f32x4 acc[2][2];
  for (int mi=0;mi<2;++mi) for (int ni=0;ni<2;++ni) acc[mi][ni] = (f32x4){0.f,0.f,0.f,0.f};

  for (int kk=0; kk<DIN; kk+=32){
    bf16x8 ahf[2], alf[2];
    for (int mi=0; mi<2; ++mi){
      int row = m0 + wm*32 + mi*16 + lm;
      const float* xp = X + (size_t)row*DIN + kk + g*8;
      f32x4 x0 = *(const f32x4*)(xp);
      f32x4 x1 = *(const f32x4*)(xp+4);
      bf16x8 ah, al;
      #pragma unroll
      for (int i=0;i<4;i++){
        unsigned short h0 = bf16_rn(x0[i]);
        ah[i] = (short)h0; al[i] = (short)bf16_rn(x0[i] - bf16_f(h0));
        unsigned short h1 = bf16_rn(x1[i]);
        ah[4+i] = (short)h1; al[4+i] = (short)bf16_rn(x1[i] - bf16_f(h1));
      }
      ahf[mi]=ah; alf[mi]=al;
    }
    #pragma unroll
    for (int ni=0; ni<2; ++ni){
      int col = n0 + wn*32 + ni*16 + lm;
      bf16x8 bh = *(const bf16x8*)(Wh + (size_t)col*DIN + kk + g*8);
      bf16x8 bl = *(const bf16x8*)(Wl + (size_t)col*DIN + kk + g*8);
      #pragma unroll
      for (int mi=0; mi<2; ++mi){
        acc[mi][ni] = __builtin_amdgcn_mfma_f32_16x16x32_bf16(ahf[mi], bh, acc[mi][ni], 0,0,0);
        if (z != 2){
          acc[mi][ni] = __builtin_amdgcn_mfma_f32_16x16x32_bf16(ahf[mi], bl, acc[mi][ni], 0,0,0);
          acc[mi][ni] = __builtin_amdgcn_mfma_f32_16x16x32_bf16(alf[mi], bh, acc[mi][ni], 0,0,0);
        }
      }
    }
  }

  for (int ni=0; ni<2; ++ni){
    int col = n0 + wn*32 + ni*16 + lm;
    float bcol = bias[col];
    int hq = col>>5, d = col&31;
    for (int mi=0; mi<2; ++mi){
      #pragma unroll
      for (int r=0; r<4; ++r){
        int row = m0 + wm*32 + mi*16 + g*4 + r;
        float v = acc[mi][ni][r] + bcol;
        if (z==0) v *= QSCALE;
        unsigned short hh = bf16_rn(v);
        if (z==0)      { unsigned short ll = bf16_rn(v - bf16_f(hh));
                         size_t p = ((size_t)hq*SQ + row)*HD + d;
                         Qhi[p]=hh; Qlo[p]=ll; }
        else if (z==1) { unsigned short ll = bf16_rn(v - bf16_f(hh));
                         size_t p = ((size_t)hq*SKK + row)*HD + d;
                         Khi[p]=hh; Klo[p]=ll; }
        else           { Vt[(size_t)col*SKK+row]=hh; }
      }
    }
  }
}

// ---------------- fused flash attention, split-K, LDS-staged K/V ----------------
// log2-domain softmax: scores arrive pre-scaled by log2e; exp2 everywhere.
__global__ __launch_bounds__(256) void attn_kernel(
    const unsigned short* __restrict__ Qhi, const unsigned short* __restrict__ Qlo,
    const unsigned short* __restrict__ Khi, const unsigned short* __restrict__ Klo,
    const unsigned short* __restrict__ Vt,
    const float* __restrict__ mask,
    float* __restrict__ opart, float* __restrict__ mpart, float* __restrict__ lpart,
    int nkt, int direct)
{
  const int qt = blockIdx.x, h = blockIdx.y, sp = blockIdx.z;
  const int tid = threadIdx.x;
  const int w = tid>>6, lane = tid&63;
  const int lm = lane&15, g = lane>>4;
  const int qrow = qt*64 + w*16 + lm;
  const int kbeg = sp*nkt*64;

  __shared__ unsigned short KhL[2][2048];
  __shared__ unsigned short KlL[2][2048];
  __shared__ unsigned short VL [2][2048];
  __shared__ unsigned short Ph[4096];     // [64 q][64 k], col ^ (((row>>1)&7)<<3)

  const unsigned short* Khg = Khi + (size_t)h*SKK*HD;
  const unsigned short* Klg = Klo + (size_t)h*SKK*HD;

  const int krow_s = tid>>2, kcol_s = (tid&3)*8;
  const int vrow_s = tid>>3, vcol_s = (tid&7)*8;
  const int kd = (tid*8) ^ (((tid>>2)&3)<<3);
  const int vd = (tid*8) ^ (((tid>>3)&7)<<3);

  u32x4 sa, sb, sc;
  float mk_nxt[4], mk_cur[4];
  auto stage_load = [&](int kb){
    sa = *(const u32x4*)(Khg + (size_t)(kb + krow_s)*HD + kcol_s);
    sb = *(const u32x4*)(Klg + (size_t)(kb + krow_s)*HD + kcol_s);
    sc = *(const u32x4*)(Vt + (size_t)(h*HD + vrow_s)*SKK + kb + vcol_s);
    #pragma unroll
    for (int ks=0; ks<4; ++ks) mk_nxt[ks] = mask[kb + ks*16 + lm] * LOG2E;
  };
  auto stage_write = [&](int b){
    *(u32x4*)(&KhL[b][kd]) = sa;
    *(u32x4*)(&KlL[b][kd]) = sb;
    *(u32x4*)(&VL [b][vd]) = sc;
  };

  bf16x8 qh = *(const bf16x8*)(Qhi + ((size_t)h*SQ + qrow)*HD + g*8);
  bf16x8 ql = *(const bf16x8*)(Qlo + ((size_t)h*SQ + qrow)*HD + g*8);

  bf16x8 ones;
  #pragma unroll
  for (int i=0;i<8;++i) ones[i] = (short)0x3F80;  // bf16 1.0

  f32x4 o0 = {0.f,0.f,0.f,0.f}, o1 = {0.f,0.f,0.f,0.f};
  f32x4 lacc = {0.f,0.f,0.f,0.f};                 // MFMA row-sums
  float m[4];
  #pragma unroll
  for (int r=0;r<4;++r) m[r] = -3.0e38f;

  stage_load(kbeg);
  stage_write(0);
  #pragma unroll
  for (int ks=0; ks<4; ++ks) mk_cur[ks] = mk_nxt[ks];
  __syncthreads();
  int cur = 0;

  const int prow = w*16 + g*4;
  const int psw  = (lm>>1)<<3;   // read-side swizzle for row q = w*16+lm

  for (int t=0; t<nkt; ++t){
    if (t+1 < nkt) stage_load(kbeg + (t+1)*64);

    // ---- scores S[16q x 64k], 3 split terms, log2-domain ----
    f32x4 s[4];
    #pragma unroll
    for (int ks=0; ks<4; ++ks){
      int kidx = ((ks*16+lm)*32 + g*8) ^ ((lm&3)<<3);
      bf16x8 kh = *(const bf16x8*)(&KhL[cur][kidx]);
      bf16x8 kl = *(const bf16x8*)(&KlL[cur][kidx]);
      f32x4 a = {0.f,0.f,0.f,0.f};
      __builtin_amdgcn_s_setprio(1);
      a = __builtin_amdgcn_mfma_f32_16x16x32_bf16(qh, kh, a, 0,0,0);
      a = __builtin_amdgcn_mfma_f32_16x16x32_bf16(qh, kl, a, 0,0,0);
      a = __builtin_amdgcn_mfma_f32_16x16x32_bf16(ql, kh, a, 0,0,0);
      __builtin_amdgcn_s_setprio(0);
      float mk = mk_cur[ks];
      #pragma unroll
      for (int r=0;r<4;++r) a[r] += mk;
      s[ks] = a;
    }

    // ---- defer-max (log2 units, thr 11.5 -> P <= 2^11.5) ----
    float tl[4];
    #pragma unroll
    for (int r=0;r<4;++r)
      tl[r] = fmaxf(fmaxf(s[0][r],s[1][r]), fmaxf(s[2][r],s[3][r]));
    bool ok = (tl[0] <= m[0]+11.5f) && (tl[1] <= m[1]+11.5f) &&
              (tl[2] <= m[2]+11.5f) && (tl[3] <= m[3]+11.5f);
    if (__ballot(ok) != ~0ULL){
      #pragma unroll
      for (int r=0;r<4;++r){
        float t2 = tl[r];
        #pragma unroll
        for (int off=1; off<16; off<<=1) t2 = fmaxf(t2, __shfl_xor(t2, off));
        float mn = fmaxf(m[r], t2);
        float sc2 = exp2f(m[r] - mn);
        o0[r] *= sc2; o1[r] *= sc2; lacc[r] *= sc2;
        m[r] = mn;
      }
    }

    // ---- P = 2^(s-m), packed bf16 convert, swizzled LDS ----
    #pragma unroll
    for (int ks=0; ks<4; ++ks){
      float p0 = exp2f(s[ks][0] - m[0]);
      float p1 = exp2f(s[ks][1] - m[1]);
      float p2 = exp2f(s[ks][2] - m[2]);
      float p3 = exp2f(s[ks][3] - m[3]);
      unsigned int c01, c23;
      asm("v_cvt_pk_bf16_f32 %0, %1, %2" : "=v"(c01) : "v"(p0), "v"(p1));
      asm("v_cvt_pk_bf16_f32 %0, %1, %2" : "=v"(c23) : "v"(p2), "v"(p3));
      const int col = ks*16 + lm;
      Ph[((prow+0)<<6) + (col ^ ((((prow+0)>>1)&7)<<3))] = (unsigned short)(c01 & 0xffffu);
      Ph[((prow+1)<<6) + (col ^ ((((prow+1)>>1)&7)<<3))] = (unsigned short)(c01 >> 16);
      Ph[((prow+2)<<6) + (col ^ ((((prow+2)>>1)&7)<<3))] = (unsigned short)(c23 & 0xffffu);
      Ph[((prow+3)<<6) + (col ^ ((((prow+3)>>1)&7)<<3))] = (unsigned short)(c23 >> 16);
    }

    // ---- PV + row-sum via ones-MFMA ----
    const int q = w*16 + lm;
    #pragma unroll
    for (int ks2=0; ks2<2; ++ks2){
      bf16x8 pa = *(const bf16x8*)&Ph[(q<<6) + ((ks2*32 + g*8) ^ psw)];
      int v0i = (lm*64      + ks2*32 + g*8) ^ ((lm&7)<<3);
      int v1i = ((lm+16)*64 + ks2*32 + g*8) ^ ((lm&7)<<3);
      bf16x8 v0 = *(const bf16x8*)(&VL[cur][v0i]);
      bf16x8 v1 = *(const bf16x8*)(&VL[cur][v1i]);
      __builtin_amdgcn_s_setprio(1);
      o0   = __builtin_amdgcn_mfma_f32_16x16x32_bf16(pa, v0,   o0,   0,0,0);
      o1   = __builtin_amdgcn_mfma_f32_16x16x32_bf16(pa, v1,   o1,   0,0,0);
      lacc = __builtin_amdgcn_mfma_f32_16x16x32_bf16(pa, ones, lacc, 0,0,0);
      __builtin_amdgcn_s_setprio(0);
    }

    if (t+1 < nkt){
      stage_write(cur^1);
      #pragma unroll
      for (int ks=0; ks<4; ++ks) mk_cur[ks] = mk_nxt[ks];
    }
    __syncthreads();
    cur ^= 1;
  }

  if (direct){
    #pragma unroll
    for (int r=0;r<4;++r){
      float inv = 1.0f / lacc[r];
      int row = qt*64 + w*16 + g*4 + r;
      opart[(size_t)row*AHS + h*HD + lm]      = o0[r]*inv;
      opart[(size_t)row*AHS + h*HD + 16 + lm] = o1[r]*inv;
    }
  } else {
    #pragma unroll
    for (int r=0;r<4;++r){
      int row = qt*64 + w*16 + g*4 + r;
      opart[((size_t)sp*SQ + row)*AHS + h*HD + lm]      = o0[r];
      opart[((size_t)sp*SQ + row)*AHS + h*HD + 16 + lm] = o1[r];
    }
    if (lm == 0){
      #pragma unroll
      for (int r=0;r<4;++r){
        int row = qt*64 + w*16 + g*4 + r;
        mpart[((size_t)sp*NHEAD + h)*SQ + row] = m[r];
        lpart[((size_t)sp*NHEAD + h)*SQ + row] = lacc[r];
      }
    }
  }
}

// ---------------- merge partial splits (log2-domain weights) ----------------
__global__ void merge_kernel(const float* __restrict__ opart,
                             const float* __restrict__ mpart,
                             const float* __restrict__ lpart,
                             float* __restrict__ out, int S){
  int idx = blockIdx.x*256 + threadIdx.x;
  if (idx >= SQ*AHS) return;
  int row = idx/AHS, c = idx - row*AHS;
  int h = c >> 5;
  float M = -3.0e38f;
  for (int s=0; s<S; ++s) M = fmaxf(M, mpart[((size_t)s*NHEAD + h)*SQ + row]);
  float num = 0.f, den = 0.f;
  for (int s=0; s<S; ++s){
    float wgt = exp2f(mpart[((size_t)s*NHEAD + h)*SQ + row] - M);
    num += wgt * opart[((size_t)s*SQ + row)*AHS + c];
    den += wgt * lpart[((size_t)s*NHEAD + h)*SQ + row];
  }
  out[idx] = num/den;
}

extern "C" void kernel_launch(void* const* d_in, const int* in_sizes, int n_in,
                              void* d_out, int out_size, void* d_ws, size_t ws_size,
                              hipStream_t stream) {
  const float* Xh   = (const float*)d_in[0];
  const float* Xe   = (const float*)d_in[1];
  const float* mask = (const float*)d_in[2];
  const float* Wq   = (const float*)d_in[3];
  const float* bq   = (const float*)d_in[4];
  const float* Wk   = (const float*)d_in[5];
  const float* bk   = (const float*)d_in[6];
  const float* Wv   = (const float*)d_in[7];
  const float* bv   = (const float*)d_in[8];
  float* out = (float*)d_out;

  char* ws = (char*)d_ws;
  auto al256 = [](size_t b)->size_t{ return (b + 255) & ~(size_t)255; };
  size_t off = 0;
  auto alloc = [&](size_t bytes)->void*{ void* p = ws + off; off += al256(bytes); return p; };

  unsigned short* Wthi = (unsigned short*)alloc((size_t)3*DIN*AHS*2);
  unsigned short* Wtlo = (unsigned short*)alloc((size_t)3*DIN*AHS*2);
  unsigned short* Qhi  = (unsigned short*)alloc((size_t)NHEAD*SQ*HD*2);
  unsigned short* Qlo  = (unsigned short*)alloc((size_t)NHEAD*SQ*HD*2);
  unsigned short* Khi  = (unsigned short*)alloc((size_t)NHEAD*SKK*HD*2);
  unsigned short* Klo  = (unsigned short*)alloc((size_t)NHEAD*SKK*HD*2);
  unsigned short* Vt   = (unsigned short*)alloc((size_t)AHS*SKK*2);
  const size_t base_end = off;

  const size_t XB = al256((size_t)SQ*DIN*2);
  const size_t OB = al256((size_t)SQ*AHS*4);
  const size_t MB = al256((size_t)NHEAD*SQ*4);
  const size_t xneed = 4*XB;

  auto fits = [&](int S, int presplit)->bool{
    size_t need_u = (size_t)S*OB + 2*(size_t)S*MB;
    if (presplit && xneed > need_u) need_u = xneed;
    return base_end + need_u + 1024 <= ws_size;
  };

  int presplit = 1, S = 1, direct = 0;
  if      (fits(8,1)) S = 8;
  else if (fits(4,1)) S = 4;
  else if (fits(2,1)) S = 2;
  else if (fits(1,1)) S = 1;
  else {
    presplit = 0;
    if      (fits(4,0)) S = 4;
    else if (fits(2,0)) S = 2;
    else if (fits(1,0)) S = 1;
    else { S = 1; direct = 1; }
  }

  char* ureg = ws + base_end;
  unsigned short* Xhh = (unsigned short*)(ureg);
  unsigned short* Xhl = (unsigned short*)(ureg + XB);
  unsigned short* Xeh = (unsigned short*)(ureg + 2*XB);
  unsigned short* Xel = (unsigned short*)(ureg + 3*XB);

  float *opart, *mpart, *lpart;
  if (!direct){
    opart = (float*)(ureg);  // aliases X-split region (disjoint lifetimes)
    mpart = (float*)(ureg + (size_t)S*OB);
    lpart = (float*)(ureg + (size_t)S*OB + (size_t)S*MB);
  } else {
    opart = out; mpart = (float*)ws; lpart = (float*)ws;
  }

  {
    int tot = 3*DIN*AHS;
    prep_wt_kernel<<<(tot+255)/256, 256, 0, stream>>>(Wq, Wk, Wv, Wthi, Wtlo);
  }
  if (presplit){
    int nthr = 2*(SQ*DIN)/8;
    split_x_kernel<<<nthr/256, 256, 0, stream>>>(Xh, Xe, Xhh, Xhl, Xeh, Xel);
    dim3 grid(SQ/128, AHS/128, 3);
    proj2_kernel<<<grid, 512, 0, stream>>>(Xhh, Xhl, Xeh, Xel, Wthi, Wtlo,
                                           bq, bk, bv, Qhi, Qlo, Khi, Klo, Vt);
  } else {
    dim3 grid(SQ/64, AHS/64, 3);
    proj_fallback_kernel<<<grid, 256, 0, stream>>>(Xh, Xe, Wthi, Wtlo, bq, bk, bv,
                                                   Qhi, Qlo, Khi, Klo, Vt);
  }
  {
    dim3 grid(SQ/64, NHEAD, S);
    int nkt = (SKK/64)/S;
    attn_kernel<<<grid, 256, 0, stream>>>(Qhi, Qlo, Khi, Klo, Vt, mask,
                                          opart, mpart, lpart, nkt, direct);
  }
  if (!direct){
    int n = SQ*AHS;
    merge_kernel<<<(n+255)/256, 256, 0, stream>>>(opart, mpart, lpart, out, S);
  }
}

// Round 6
// 155.734 us; speedup vs baseline: 3.0112x; 1.2460x over previous
//
#include <hip/hip_runtime.h>
#include <hip/hip_bf16.h>

#define SQ 4096
#define SKK 4096
#define DIN 768
#define AHS 384
#define NHEAD 12
#define HD 32

typedef __attribute__((ext_vector_type(8))) short bf16x8;
typedef __attribute__((ext_vector_type(4))) float f32x4;
typedef __attribute__((ext_vector_type(4))) unsigned int u32x4;

#define LOG2E 1.4426950408889634f
// log2(e)/sqrt(32): folds the 1/sqrt(d) score scale and exp->exp2 into Q.
#define QSCALE 0.25503486168652855f

__device__ __forceinline__ unsigned short bf16_rn(float x){
  unsigned int u = __float_as_uint(x);
  unsigned int r = u + 0x7fffu + ((u>>16)&1u);
  return (unsigned short)(r>>16);
}
__device__ __forceinline__ float bf16_f(unsigned short h){
  return __uint_as_float(((unsigned int)h)<<16);
}
__device__ __forceinline__ float fexp2(float x){
#if __has_builtin(__builtin_amdgcn_exp2f)
  return __builtin_amdgcn_exp2f(x);      // bare v_exp_f32
#else
  float r; asm("v_exp_f32 %0, %1" : "=v"(r) : "v"(x)); return r;
#endif
}

// ---------------- prep: W -> W^T split into bf16 hi/lo ----------------
__global__ void prep_wt_kernel(const float* __restrict__ Wq, const float* __restrict__ Wk,
                               const float* __restrict__ Wv,
                               unsigned short* __restrict__ Wthi, unsigned short* __restrict__ Wtlo){
  int idx = blockIdx.x*256 + threadIdx.x;
  const int per = DIN*AHS;
  if (idx >= 3*per) return;
  int mat = idx/per, rem = idx - mat*per;
  int k = rem/AHS, n = rem - k*AHS;
  const float* W = (mat==0)?Wq:((mat==1)?Wk:Wv);
  float v = W[k*AHS+n];
  unsigned short hh = bf16_rn(v);
  unsigned short ll = bf16_rn(v - bf16_f(hh));
  Wthi[mat*per + n*DIN + k] = hh;
  Wtlo[mat*per + n*DIN + k] = ll;
}

// ---------------- split X (fp32) -> bf16 hi/lo, 8 elems/thread ----------------
__global__ void split_x_kernel(const float* __restrict__ Xh, const float* __restrict__ Xe,
                               unsigned short* __restrict__ Xhh, unsigned short* __restrict__ Xhl,
                               unsigned short* __restrict__ Xeh, unsigned short* __restrict__ Xel){
  const int n8 = (SQ*DIN)/8;
  int t = blockIdx.x*256 + threadIdx.x;
  const float* src; unsigned short *dh, *dl; int i;
  if (t < n8){ src = Xh; dh = Xhh; dl = Xhl; i = t; }
  else       { src = Xe; dh = Xeh; dl = Xel; i = t - n8; }
  f32x4 x0 = *(const f32x4*)(src + (size_t)i*8);
  f32x4 x1 = *(const f32x4*)(src + (size_t)i*8 + 4);
  bf16x8 hi, lo;
  #pragma unroll
  for (int j=0;j<4;++j){
    unsigned short h0 = bf16_rn(x0[j]);
    hi[j]   = (short)h0; lo[j]   = (short)bf16_rn(x0[j] - bf16_f(h0));
    unsigned short h1 = bf16_rn(x1[j]);
    hi[4+j] = (short)h1; lo[4+j] = (short)bf16_rn(x1[j] - bf16_f(h1));
  }
  *(bf16x8*)(dh + (size_t)i*8) = hi;
  *(bf16x8*)(dl + (size_t)i*8) = lo;
}

// ---------------- proj2: 128x128 tile, 8 waves, LDS double-buffered ----------------
__global__ __launch_bounds__(512,4) void proj2_kernel(
    const unsigned short* __restrict__ Xhh, const unsigned short* __restrict__ Xhl,
    const unsigned short* __restrict__ Xeh, const unsigned short* __restrict__ Xel,
    const unsigned short* __restrict__ Wthi, const unsigned short* __restrict__ Wtlo,
    const float* __restrict__ bq, const float* __restrict__ bk, const float* __restrict__ bv,
    unsigned short* __restrict__ Qhi, unsigned short* __restrict__ Qlo,
    unsigned short* __restrict__ Khi, unsigned short* __restrict__ Klo,
    unsigned short* __restrict__ Vt)
{
  const int z = blockIdx.z;
  const unsigned short* Ah = (z==0) ? Xhh : Xeh;
  const unsigned short* Al = (z==0) ? Xhl : Xel;
  const unsigned short* Bh = Wthi + (size_t)z*(DIN*AHS);
  const unsigned short* Bl = Wtlo + (size_t)z*(DIN*AHS);
  const float* bias = (z==0) ? bq : ((z==1) ? bk : bv);

  const int m0 = blockIdx.x*128;
  const int n0 = blockIdx.y*128;
  const int tid = threadIdx.x;
  const int w = tid>>6, lane = tid&63;
  const int lm = lane&15, g = lane>>4;
  const int wm = w>>1, wn = w&1;   // 4m x 2n waves, wave tile 32x64

  __shared__ __align__(16) unsigned short SH[32768];

  const int srow = tid>>2, scol = (tid&3)*8;
  const size_t ga = (size_t)(m0 + srow)*DIN + scol;
  const size_t gb = (size_t)(n0 + srow)*DIN + scol;
  const int sidx = srow*32 + scol;

  u32x4 ra, rla, rb, rlb;
  auto sload = [&](int kk){
    ra = *(const u32x4*)(Ah + ga + kk);
    rb = *(const u32x4*)(Bh + gb + kk);
    if (z != 2){
      rla = *(const u32x4*)(Al + ga + kk);
      rlb = *(const u32x4*)(Bl + gb + kk);
    }
  };
  auto swrite = [&](int b){
    *(u32x4*)&SH[b*16384 + 0*4096 + sidx] = ra;
    *(u32x4*)&SH[b*16384 + 2*4096 + sidx] = rb;
    if (z != 2){
      *(u32x4*)&SH[b*16384 + 1*4096 + sidx] = rla;
      *(u32x4*)&SH[b*16384 + 3*4096 + sidx] = rlb;
    }
  };

  f32x4 acc[2][4];
  #pragma unroll
  for (int mi=0;mi<2;++mi)
    #pragma unroll
    for (int ni=0;ni<4;++ni) acc[mi][ni] = (f32x4){0.f,0.f,0.f,0.f};

  sload(0); swrite(0); __syncthreads();
  int cur = 0;

  const int NKS = DIN/32;  // 24
  for (int t=0; t<NKS; ++t){
    if (t+1 < NKS) sload((t+1)*32);

    const unsigned short* AhL = &SH[cur*16384 + 0*4096];
    const unsigned short* AlL = &SH[cur*16384 + 1*4096];
    const unsigned short* BhL = &SH[cur*16384 + 2*4096];
    const unsigned short* BlL = &SH[cur*16384 + 3*4096];

    bf16x8 a0h = *(const bf16x8*)&AhL[(wm*32 + lm)*32 + g*8];
    bf16x8 a1h = *(const bf16x8*)&AhL[(wm*32 + 16 + lm)*32 + g*8];
    bf16x8 a0l, a1l;
    if (z != 2){
      a0l = *(const bf16x8*)&AlL[(wm*32 + lm)*32 + g*8];
      a1l = *(const bf16x8*)&AlL[(wm*32 + 16 + lm)*32 + g*8];
    }
    __builtin_amdgcn_s_setprio(1);
    #pragma unroll
    for (int ni=0; ni<4; ++ni){
      bf16x8 bh = *(const bf16x8*)&BhL[(wn*64 + ni*16 + lm)*32 + g*8];
      acc[0][ni] = __builtin_amdgcn_mfma_f32_16x16x32_bf16(a0h, bh, acc[0][ni], 0,0,0);
      acc[1][ni] = __builtin_amdgcn_mfma_f32_16x16x32_bf16(a1h, bh, acc[1][ni], 0,0,0);
      if (z != 2){
        bf16x8 bl = *(const bf16x8*)&BlL[(wn*64 + ni*16 + lm)*32 + g*8];
        acc[0][ni] = __builtin_amdgcn_mfma_f32_16x16x32_bf16(a0h, bl, acc[0][ni], 0,0,0);
        acc[1][ni] = __builtin_amdgcn_mfma_f32_16x16x32_bf16(a1h, bl, acc[1][ni], 0,0,0);
        acc[0][ni] = __builtin_amdgcn_mfma_f32_16x16x32_bf16(a0l, bh, acc[0][ni], 0,0,0);
        acc[1][ni] = __builtin_amdgcn_mfma_f32_16x16x32_bf16(a1l, bh, acc[1][ni], 0,0,0);
      }
    }
    __builtin_amdgcn_s_setprio(0);

    if (t+1 < NKS) swrite(cur^1);
    __syncthreads();
    cur ^= 1;
  }

  if (z != 2){
    #pragma unroll
    for (int ni=0; ni<4; ++ni){
      int col = n0 + wn*64 + ni*16 + lm;
      float bcol = bias[col];
      int hq = col>>5, d = col&31;
      #pragma unroll
      for (int mi=0; mi<2; ++mi){
        #pragma unroll
        for (int r=0; r<4; ++r){
          int row = m0 + wm*32 + mi*16 + g*4 + r;
          float v = acc[mi][ni][r] + bcol;
          if (z==0) v *= QSCALE;
          unsigned short hh = bf16_rn(v);
          unsigned short ll = bf16_rn(v - bf16_f(hh));
          size_t p = (z==0) ? ((size_t)hq*SQ + row)*HD + d
                            : ((size_t)hq*SKK + row)*HD + d;
          if (z==0){ Qhi[p]=hh; Qlo[p]=ll; } else { Khi[p]=hh; Klo[p]=ll; }
        }
      }
    }
  } else {
    #pragma unroll
    for (int ni=0; ni<4; ++ni){
      int lcol = wn*64 + ni*16 + lm;
      float bcol = bias[n0 + lcol];
      #pragma unroll
      for (int mi=0; mi<2; ++mi){
        #pragma unroll
        for (int r=0; r<4; ++r){
          int lrow = wm*32 + mi*16 + g*4 + r;
          SH[lcol*128 + (lrow ^ ((lcol&7)<<3))] = bf16_rn(acc[mi][ni][r] + bcol);
        }
      }
    }
    __syncthreads();
    #pragma unroll
    for (int p=0; p<4; ++p){
      int c = tid>>2, rc = (tid&3)*8 + p*32;
      bf16x8 vv = *(const bf16x8*)&SH[c*128 + (rc ^ ((c&7)<<3))];
      *(bf16x8*)(Vt + (size_t)(n0 + c)*SKK + m0 + rc) = vv;
    }
  }
}

// ---------------- fallback proj (low-ws) ----------------
__global__ __launch_bounds__(256) void proj_fallback_kernel(
    const float* __restrict__ Xh, const float* __restrict__ Xe,
    const unsigned short* __restrict__ Wthi, const unsigned short* __restrict__ Wtlo,
    const float* __restrict__ bq, const float* __restrict__ bk, const float* __restrict__ bv,
    unsigned short* __restrict__ Qhi, unsigned short* __restrict__ Qlo,
    unsigned short* __restrict__ Khi, unsigned short* __restrict__ Klo,
    unsigned short* __restrict__ Vt)
{
  const int z = blockIdx.z;
  const float* X    = (z==0) ? Xh : Xe;
  const float* bias = (z==0) ? bq : ((z==1) ? bk : bv);
  const unsigned short* Wh = Wthi + (size_t)z*(DIN*AHS);
  const unsigned short* Wl = Wtlo + (size_t)z*(DIN*AHS);

  const int m0 = blockIdx.x*64;
  const int n0 = blockIdx.y*64;
  const int w  = threadIdx.x>>6, lane = threadIdx.x&63;
  const int lm = lane&15, g = lane>>4;
  const int wm = w>>1, wn = w&1;

  f32x4 acc[2][2];
  for (int mi=0;mi<2;++mi) for (int ni=0;ni<2;++ni) acc[mi][ni] = (f32x4){0.f,0.f,0.f,0.f};

  for (int kk=0; kk<DIN; kk+=32){
    bf16x8 ahf[2], alf[2];
    for (int mi=0; mi<2; ++mi){
      int row = m0 + wm*32 + mi*16 + lm;
      const float* xp = X + (size_t)row*DIN + kk + g*8;
      f32x4 x0 = *(const f32x4*)(xp);
      f32x4 x1 = *(const f32x4*)(xp+4);
      bf16x8 ah, al;
      #pragma unroll
      for (int i=0;i<4;i++){
        unsigned short h0 = bf16_rn(x0[i]);
        ah[i] = (short)h0; al[i] = (short)bf16_rn(x0[i] - bf16_f(h0));
        unsigned short h1 = bf16_rn(x1[i]);
        ah[4+i] = (short)h1; al[4+i] = (short)bf16_rn(x1[i] - bf16_f(h1));
      }
      ahf[mi]=ah; alf[mi]=al;
    }
    #pragma unroll
    for (int ni=0; ni<2; ++ni){
      int col = n0 + wn*32 + ni*16 + lm;
      bf16x8 bh = *(const bf16x8*)(Wh + (size_t)col*DIN + kk + g*8);
      bf16x8 bl = *(const bf16x8*)(Wl + (size_t)col*DIN + kk + g*8);
      #pragma unroll
      for (int mi=0; mi<2; ++mi){
        acc[mi][ni] = __builtin_amdgcn_mfma_f32_16x16x32_bf16(ahf[mi], bh, acc[mi][ni], 0,0,0);
        if (z != 2){
          acc[mi][ni] = __builtin_amdgcn_mfma_f32_16x16x32_bf16(ahf[mi], bl, acc[mi][ni], 0,0,0);
          acc[mi][ni] = __builtin_amdgcn_mfma_f32_16x16x32_bf16(alf[mi], bh, acc[mi][ni], 0,0,0);
        }
      }
    }
  }

  for (int ni=0; ni<2; ++ni){
    int col = n0 + wn*32 + ni*16 + lm;
    float bcol = bias[col];
    int hq = col>>5, d = col&31;
    for (int mi=0; mi<2; ++mi){
      #pragma unroll
      for (int r=0; r<4; ++r){
        int row = m0 + wm*32 + mi*16 + g*4 + r;
        float v = acc[mi][ni][r] + bcol;
        if (z==0) v *= QSCALE;
        unsigned short hh = bf16_rn(v);
        if (z==0)      { unsigned short ll = bf16_rn(v - bf16_f(hh));
                         size_t p = ((size_t)hq*SQ + row)*HD + d;
                         Qhi[p]=hh; Qlo[p]=ll; }
        else if (z==1) { unsigned short ll = bf16_rn(v - bf16_f(hh));
                         size_t p = ((size_t)hq*SKK + row)*HD + d;
                         Khi[p]=hh; Klo[p]=ll; }
        else           { Vt[(size_t)col*SKK+row]=hh; }
      }
    }
  }
}

// ---------------- fused flash attention: swapped QK^T, in-register P ----------------
// mfma(K,Q): lane(g,lm) holds S[q=lm][key = 32*(ks>>1) + g*8 + (ks&1)*4 + r]
// via permuted K-row reads, so exp'd P values ARE the PV A-fragment. No P LDS.
__global__ __launch_bounds__(256) void attn_kernel(
    const unsigned short* __restrict__ Qhi, const unsigned short* __restrict__ Qlo,
    const unsigned short* __restrict__ Khi, const unsigned short* __restrict__ Klo,
    const unsigned short* __restrict__ Vt,
    const float* __restrict__ mask,
    float* __restrict__ opart, float* __restrict__ mpart, float* __restrict__ lpart,
    int nkt, int direct)
{
  const int qt = blockIdx.x, h = blockIdx.y, sp = blockIdx.z;
  const int tid = threadIdx.x;
  const int w = tid>>6, lane = tid&63;
  const int lm = lane&15, g = lane>>4;
  const int qrow = qt*64 + w*16 + lm;
  const int kbeg = sp*nkt*64;

  __shared__ unsigned short KhL[2][2048];
  __shared__ unsigned short KlL[2][2048];
  __shared__ unsigned short VL [2][2048];

  const unsigned short* Khg = Khi + (size_t)h*SKK*HD;
  const unsigned short* Klg = Klo + (size_t)h*SKK*HD;

  const int krow_s = tid>>2, kcol_s = (tid&3)*8;
  const int vrow_s = tid>>3, vcol_s = (tid&7)*8;
  const int kd = (tid*8) ^ (((tid>>2)&3)<<3);
  const int vd = (tid*8) ^ (((tid>>3)&7)<<3);

  u32x4 sa, sb, sc;
  auto stage_load = [&](int kb){
    sa = *(const u32x4*)(Khg + (size_t)(kb + krow_s)*HD + kcol_s);
    sb = *(const u32x4*)(Klg + (size_t)(kb + krow_s)*HD + kcol_s);
    sc = *(const u32x4*)(Vt + (size_t)(h*HD + vrow_s)*SKK + kb + vcol_s);
  };
  auto stage_write = [&](int b){
    *(u32x4*)(&KhL[b][kd]) = sa;
    *(u32x4*)(&KlL[b][kd]) = sb;
    *(u32x4*)(&VL [b][vd]) = sc;
  };

  bf16x8 qh = *(const bf16x8*)(Qhi + ((size_t)h*SQ + qrow)*HD + g*8);
  bf16x8 ql = *(const bf16x8*)(Qlo + ((size_t)h*SQ + qrow)*HD + g*8);

  bf16x8 ones;
  #pragma unroll
  for (int i=0;i<8;++i) ones[i] = (short)0x3F80;  // bf16 1.0

  // Permuted K-row LDS offsets: key(ks,lm) = 32*(ks>>1) + (lm>>2)*8 + (ks&1)*4 + (lm&3).
  // key&3 == lm&3, so the write-side ^((row&3)<<3) swizzle is matched.
  int kidx[4];
  #pragma unroll
  for (int ks=0; ks<4; ++ks){
    int krow = ((ks>>1)<<5) + ((lm>>2)<<3) + ((ks&1)<<2) + (lm&3);
    kidx[ks] = (krow*32 + g*8) ^ ((lm&3)<<3);
  }

  f32x4 o0 = {0.f,0.f,0.f,0.f}, o1 = {0.f,0.f,0.f,0.f};
  f32x4 lacc = {0.f,0.f,0.f,0.f};
  float m = -3.0e38f;

  stage_load(kbeg);
  stage_write(0);
  __syncthreads();
  int cur = 0;

  for (int t=0; t<nkt; ++t){
    const int kt = kbeg + t*64;
    if (t+1 < nkt) stage_load(kt + 64);

    // mask values for this lane's 16 keys (L2-hot; issued before MFMAs)
    f32x4 mkv[4];
    #pragma unroll
    for (int ks=0; ks<4; ++ks)
      mkv[ks] = *(const f32x4*)(mask + kt + ((ks>>1)<<5) + g*8 + ((ks&1)<<2));

    // ---- scores: swapped, permuted-row K as A-operand, 3 split terms ----
    f32x4 s[4];
    #pragma unroll
    for (int ks=0; ks<4; ++ks){
      bf16x8 kh = *(const bf16x8*)(&KhL[cur][kidx[ks]]);
      bf16x8 kl = *(const bf16x8*)(&KlL[cur][kidx[ks]]);
      f32x4 a = {0.f,0.f,0.f,0.f};
      __builtin_amdgcn_s_setprio(1);
      a = __builtin_amdgcn_mfma_f32_16x16x32_bf16(kh, qh, a, 0,0,0);
      a = __builtin_amdgcn_mfma_f32_16x16x32_bf16(kh, ql, a, 0,0,0);
      a = __builtin_amdgcn_mfma_f32_16x16x32_bf16(kl, qh, a, 0,0,0);
      __builtin_amdgcn_s_setprio(0);
      #pragma unroll
      for (int r=0;r<4;++r) a[r] = fmaf(mkv[ks][r], LOG2E, a[r]);
      s[ks] = a;
    }

    // ---- defer-max: in-lane max of 16, ballot fast path ----
    float tl = fmaxf(
      fmaxf(fmaxf(fmaxf(s[0][0],s[0][1]),fmaxf(s[0][2],s[0][3])),
            fmaxf(fmaxf(s[1][0],s[1][1]),fmaxf(s[1][2],s[1][3]))),
      fmaxf(fmaxf(fmaxf(s[2][0],s[2][1]),fmaxf(s[2][2],s[2][3])),
            fmaxf(fmaxf(s[3][0],s[3][1]),fmaxf(s[3][2],s[3][3]))));
    bool ok = tl <= m + 11.5f;
    if (__ballot(ok) != ~0ULL){
      float t2 = fmaxf(tl, __shfl_xor(tl, 16));
      t2 = fmaxf(t2, __shfl_xor(t2, 32));
      float mn = fmaxf(m, t2);
      float scx = fexp2(m - mn);
      m = mn;
      #pragma unroll
      for (int r=0;r<4;++r){
        float scq = __shfl(scx, g*4 + r);   // scale for q = g*4+r
        o0[r] *= scq; o1[r] *= scq; lacc[r] *= scq;
      }
    }

    // ---- P = 2^(s-m) -> packed bf16; directly the PV A-fragments ----
    unsigned int wds[8];
    #pragma unroll
    for (int ks=0; ks<4; ++ks){
      float p0 = fexp2(s[ks][0] - m);
      float p1 = fexp2(s[ks][1] - m);
      float p2 = fexp2(s[ks][2] - m);
      float p3 = fexp2(s[ks][3] - m);
      unsigned int c01, c23;
      asm("v_cvt_pk_bf16_f32 %0, %1, %2" : "=v"(c01) : "v"(p0), "v"(p1));
      asm("v_cvt_pk_bf16_f32 %0, %1, %2" : "=v"(c23) : "v"(p2), "v"(p3));
      wds[ks*2]   = c01;
      wds[ks*2+1] = c23;
    }
    union PU { unsigned int u[8]; bf16x8 b[2]; } pu;
    #pragma unroll
    for (int i=0;i<8;++i) pu.u[i] = wds[i];

    // ---- PV + row-sum via ones-MFMA ----
    #pragma unroll
    for (int ks2=0; ks2<2; ++ks2){
      bf16x8 pa = pu.b[ks2];
      int vi0 = (lm*64      + ks2*32 + g*8) ^ ((lm&7)<<3);
      int vi1 = ((lm+16)*64 + ks2*32 + g*8) ^ ((lm&7)<<3);
      bf16x8 v0 = *(const bf16x8*)(&VL[cur][vi0]);
      bf16x8 v1 = *(const bf16x8*)(&VL[cur][vi1]);
      __builtin_amdgcn_s_setprio(1);
      o0   = __builtin_amdgcn_mfma_f32_16x16x32_bf16(pa, v0,   o0,   0,0,0);
      o1   = __builtin_amdgcn_mfma_f32_16x16x32_bf16(pa, v1,   o1,   0,0,0);
      lacc = __builtin_amdgcn_mfma_f32_16x16x32_bf16(pa, ones, lacc, 0,0,0);
      __builtin_amdgcn_s_setprio(0);
    }

    if (t+1 < nkt) stage_write(cur^1);
    __syncthreads();
    cur ^= 1;
  }

  if (direct){
    #pragma unroll
    for (int r=0;r<4;++r){
      float inv = 1.0f / lacc[r];
      int row = qt*64 + w*16 + g*4 + r;
      opart[(size_t)row*AHS + h*HD + lm]      = o0[r]*inv;
      opart[(size_t)row*AHS + h*HD + 16 + lm] = o1[r]*inv;
    }
  } else {
    #pragma unroll
    for (int r=0;r<4;++r){
      int row = qt*64 + w*16 + g*4 + r;
      opart[((size_t)sp*SQ + row)*AHS + h*HD + lm]      = o0[r];
      opart[((size_t)sp*SQ + row)*AHS + h*HD + 16 + lm] = o1[r];
    }
    float mq[4];
    #pragma unroll
    for (int r=0;r<4;++r) mq[r] = __shfl(m, g*4 + r);
    if (lm == 0){
      #pragma unroll
      for (int r=0;r<4;++r){
        int row = qt*64 + w*16 + g*4 + r;
        mpart[((size_t)sp*NHEAD + h)*SQ + row] = mq[r];
        lpart[((size_t)sp*NHEAD + h)*SQ + row] = lacc[r];
      }
    }
  }
}

// ---------------- merge partial splits (log2-domain weights) ----------------
__global__ void merge_kernel(const float* __restrict__ opart,
                             const float* __restrict__ mpart,
                             const float* __restrict__ lpart,
                             float* __restrict__ out, int S){
  int idx = blockIdx.x*256 + threadIdx.x;
  if (idx >= SQ*AHS) return;
  int row = idx/AHS, c = idx - row*AHS;
  int h = c >> 5;
  float M = -3.0e38f;
  for (int s=0; s<S; ++s) M = fmaxf(M, mpart[((size_t)s*NHEAD + h)*SQ + row]);
  float num = 0.f, den = 0.f;
  for (int s=0; s<S; ++s){
    float wgt = fexp2(mpart[((size_t)s*NHEAD + h)*SQ + row] - M);
    num += wgt * opart[((size_t)s*SQ + row)*AHS + c];
    den += wgt * lpart[((size_t)s*NHEAD + h)*SQ + row];
  }
  out[idx] = num/den;
}

extern "C" void kernel_launch(void* const* d_in, const int* in_sizes, int n_in,
                              void* d_out, int out_size, void* d_ws, size_t ws_size,
                              hipStream_t stream) {
  const float* Xh   = (const float*)d_in[0];
  const float* Xe   = (const float*)d_in[1];
  const float* mask = (const float*)d_in[2];
  const float* Wq   = (const float*)d_in[3];
  const float* bq   = (const float*)d_in[4];
  const float* Wk   = (const float*)d_in[5];
  const float* bk   = (const float*)d_in[6];
  const float* Wv   = (const float*)d_in[7];
  const float* bv   = (const float*)d_in[8];
  float* out = (float*)d_out;

  char* ws = (char*)d_ws;
  auto al256 = [](size_t b)->size_t{ return (b + 255) & ~(size_t)255; };
  size_t off = 0;
  auto alloc = [&](size_t bytes)->void*{ void* p = ws + off; off += al256(bytes); return p; };

  unsigned short* Wthi = (unsigned short*)alloc((size_t)3*DIN*AHS*2);
  unsigned short* Wtlo = (unsigned short*)alloc((size_t)3*DIN*AHS*2);
  unsigned short* Qhi  = (unsigned short*)alloc((size_t)NHEAD*SQ*HD*2);
  unsigned short* Qlo  = (unsigned short*)alloc((size_t)NHEAD*SQ*HD*2);
  unsigned short* Khi  = (unsigned short*)alloc((size_t)NHEAD*SKK*HD*2);
  unsigned short* Klo  = (unsigned short*)alloc((size_t)NHEAD*SKK*HD*2);
  unsigned short* Vt   = (unsigned short*)alloc((size_t)AHS*SKK*2);
  const size_t base_end = off;

  const size_t XB = al256((size_t)SQ*DIN*2);
  const size_t OB = al256((size_t)SQ*AHS*4);
  const size_t MB = al256((size_t)NHEAD*SQ*4);
  const size_t xneed = 4*XB;

  auto fits = [&](int S, int presplit)->bool{
    size_t need_u = (size_t)S*OB + 2*(size_t)S*MB;
    if (presplit && xneed > need_u) need_u = xneed;
    return base_end + need_u + 1024 <= ws_size;
  };

  int presplit = 1, S = 1, direct = 0;
  if      (fits(8,1)) S = 8;
  else if (fits(4,1)) S = 4;
  else if (fits(2,1)) S = 2;
  else if (fits(1,1)) S = 1;
  else {
    presplit = 0;
    if      (fits(4,0)) S = 4;
    else if (fits(2,0)) S = 2;
    else if (fits(1,0)) S = 1;
    else { S = 1; direct = 1; }
  }

  char* ureg = ws + base_end;
  unsigned short* Xhh = (unsigned short*)(ureg);
  unsigned short* Xhl = (unsigned short*)(ureg + XB);
  unsigned short* Xeh = (unsigned short*)(ureg + 2*XB);
  unsigned short* Xel = (unsigned short*)(ureg + 3*XB);

  float *opart, *mpart, *lpart;
  if (!direct){
    opart = (float*)(ureg);  // aliases X-split region (disjoint lifetimes)
    mpart = (float*)(ureg + (size_t)S*OB);
    lpart = (float*)(ureg + (size_t)S*OB + (size_t)S*MB);
  } else {
    opart = out; mpart = (float*)ws; lpart = (float*)ws;
  }

  {
    int tot = 3*DIN*AHS;
    prep_wt_kernel<<<(tot+255)/256, 256, 0, stream>>>(Wq, Wk, Wv, Wthi, Wtlo);
  }
  if (presplit){
    int nthr = 2*(SQ*DIN)/8;
    split_x_kernel<<<nthr/256, 256, 0, stream>>>(Xh, Xe, Xhh, Xhl, Xeh, Xel);
    dim3 grid(SQ/128, AHS/128, 3);
    proj2_kernel<<<grid, 512, 0, stream>>>(Xhh, Xhl, Xeh, Xel, Wthi, Wtlo,
                                           bq, bk, bv, Qhi, Qlo, Khi, Klo, Vt);
  } else {
    dim3 grid(SQ/64, AHS/64, 3);
    proj_fallback_kernel<<<grid, 256, 0, stream>>>(Xh, Xe, Wthi, Wtlo, bq, bk, bv,
                                                   Qhi, Qlo, Khi, Klo, Vt);
  }
  {
    dim3 grid(SQ/64, NHEAD, S);
    int nkt = (SKK/64)/S;
    attn_kernel<<<grid, 256, 0, stream>>>(Qhi, Qlo, Khi, Klo, Vt, mask,
                                          opart, mpart, lpart, nkt, direct);
  }
  if (!direct){
    int n = SQ*AHS;
    merge_kernel<<<(n+255)/256, 256, 0, stream>>>(opart, mpart, lpart, out, S);
  }
}